// Round 5
// baseline (987.004 us; speedup 1.0000x reference)
//
#include <hip/hip_runtime.h>
#include <hip/hip_bf16.h>
#include <hip/hip_fp8.h>
#include <stdint.h>
#include <type_traits>

#define NIN  1024
#define NOUT 1024
#define NB   4096   // batch

typedef float f32x4 __attribute__((ext_vector_type(4)));
typedef __bf16 bf16x8 __attribute__((ext_vector_type(8)));
typedef int   i32x4 __attribute__((ext_vector_type(4)));
typedef int   i32x8 __attribute__((ext_vector_type(8)));

typedef const __attribute__((address_space(1))) unsigned int* gp1_t;
typedef __attribute__((address_space(3))) unsigned int* lp3_t;

__device__ __forceinline__ void gload16(const void* g, void* l) {
    __builtin_amdgcn_global_load_lds((gp1_t)g, (lp3_t)l, 16, 0, 0);
}

__device__ __forceinline__ unsigned short f2bf(float f) {
    __bf16 h = (__bf16)f;
    return __builtin_bit_cast(unsigned short, h);
}

// pack 4 floats -> 4 e4m3fn bytes
__device__ __forceinline__ unsigned int pk4_fp8(float a, float b, float c, float d) {
#if __has_builtin(__builtin_amdgcn_cvt_pk_fp8_f32)
    int p = __builtin_amdgcn_cvt_pk_fp8_f32(a, b, 0, false);
    p = __builtin_amdgcn_cvt_pk_fp8_f32(c, d, p, true);
    return (unsigned int)p;
#else
    __hip_fp8_e4m3 qa(a), qb(b), qc(c), qd(d);
    return (unsigned int)qa.__x | ((unsigned int)qb.__x << 8) |
           ((unsigned int)qc.__x << 16) | ((unsigned int)qd.__x << 24);
#endif
}

#define BAR  __builtin_amdgcn_s_barrier()
#define LGK0 do { asm volatile("s_waitcnt lgkmcnt(0)" ::: "memory"); __builtin_amdgcn_sched_barrier(0); } while (0)
#define VMW2 do { asm volatile("s_waitcnt vmcnt(2)" ::: "memory");   __builtin_amdgcn_sched_barrier(0); } while (0)
#define VMW0 do { asm volatile("s_waitcnt vmcnt(0)" ::: "memory");   __builtin_amdgcn_sched_barrier(0); } while (0)

// ---- prep: f32 -> bf16 (generic, exact grid = n/1024 blocks) ----
__global__ void cvt_x_kernel(const float* __restrict__ x, unsigned short* __restrict__ xb) {
    int i = blockIdx.x * blockDim.x + threadIdx.x;
    f32x4 v = reinterpret_cast<const f32x4*>(x)[i];
    ushort4 o;
    o.x = f2bf(v.x); o.y = f2bf(v.y); o.z = f2bf(v.z); o.w = f2bf(v.w);
    reinterpret_cast<ushort4*>(xb)[i] = o;
}

// ---- prep: x -> fp8 e4m3 ----
__global__ void cvt_x_fp8(const float* __restrict__ x, unsigned int* __restrict__ xf8) {
    int i = blockIdx.x * blockDim.x + threadIdx.x;
    f32x4 v = reinterpret_cast<const f32x4*>(x)[i];
    xf8[i] = pk4_fp8(v.x, v.y, v.z, v.w);
}

// ---- prep: rf8[c,o,i] = fp8( exp(wls[o,i]) * r1[s0+c,o,i] )  (sigma folded in) ----
__global__ void cvt_r1_fp8(const float* __restrict__ wls, const float* __restrict__ r1,
                           unsigned int* __restrict__ rf8, int s0) {
    int idx = blockIdx.x * blockDim.x + threadIdx.x;   // 4-elt unit within chunk
    int i4 = idx & 262143;          // NOUT*NIN/4 per sample
    int c  = idx >> 18;
    f32x4 ls = reinterpret_cast<const f32x4*>(wls)[i4];
    const f32x4* rp = reinterpret_cast<const f32x4*>(r1 + ((size_t)(s0 + c) << 20));
    f32x4 r = rp[i4];
    rf8[idx] = pk4_fp8(__expf(ls.x) * r.x, __expf(ls.y) * r.y,
                       __expf(ls.z) * r.z, __expf(ls.w) * r.w);
}

// ---- prep: bias[s,o] = b_mu[o] + exp(b_ls[o]) * r2[s,o] ----
__global__ void bias_kernel(const float* __restrict__ bmu, const float* __restrict__ bls,
                            const float* __restrict__ r2, float* __restrict__ bias, int total) {
    int i = blockIdx.x * blockDim.x + threadIdx.x;
    if (i < total) {
        int o = i & (NOUT - 1);
        bias[i] = bmu[o] + __expf(bls[o]) * r2[i];
    }
}

// =====================================================================
// bf16 256x256 8-phase GEMM (r2-proven schedule). RAW=true: write acc
// directly (used for y0 = x . w_mu^T). RAW=false: += bias (legacy).
// =====================================================================
template <bool RAW>
__launch_bounds__(512, 2)
__global__ void gemm256(const unsigned short* __restrict__ xb,
                        const unsigned short* __restrict__ wb,
                        const float* __restrict__ bias,
                        float* __restrict__ out, int s0, int nwg) {
    __shared__ __align__(16) char smem[131072];
    const int tid = threadIdx.x;
    const int l   = tid & 63;
    const int w   = tid >> 6;
    const int wr  = w >> 2, wc = w & 3;

    const int b   = blockIdx.x;
    const int q8  = nwg >> 3;
    const int g   = (b & 7) * q8 + (b >> 3);
    const int mi  = g & 15;
    const int ni  = g >> 4;
    const int m0  = mi * 256;
    const int n0  = ni * 256;

    const int srow = l >> 3;
    const int scol = ((l & 7) ^ srow) * 8;            // bf16 elements
    const size_t slane = (size_t)srow * NIN + scol;

    const int rowp  = (l & 15) * 128;
    const int colp0 = ((l >> 4) ^ (l & 7)) << 4;

    f32x4 acc[8][4] = {};
    bf16x8 aF[4][2], b0F[2][2], b1F[2][2];

    const unsigned short* xbase = xb + (size_t)m0 * NIN;
    const unsigned short* wbase = wb + (size_t)n0 * NIN;

    auto STAGE = [&](int buf, int kt, int q) {
        const int R = (q & 3) * 64 + w * 8;
        const unsigned short* src = ((q < 4) ? xbase : wbase)
                                    + (size_t)R * NIN + kt * 64 + slane;
        char* dst = smem + buf * 65536 + ((q >= 4) ? 32768 : 0) + R * 128;
        gload16(src, dst);
    };
    auto LDA = [&](int buf, int mh) {
        const char* base = smem + buf * 65536 + (wr * 128 + mh * 64) * 128 + rowp;
        #pragma unroll
        for (int mb = 0; mb < 4; ++mb) {
            aF[mb][0] = *(const bf16x8*)(base + mb * 2048 + colp0);
            aF[mb][1] = *(const bf16x8*)(base + mb * 2048 + (colp0 ^ 64));
        }
    };
    auto LDB = [&](bf16x8 (&bF)[2][2], int buf, int nh) {
        const char* base = smem + buf * 65536 + 32768 + (wc * 64 + nh * 32) * 128 + rowp;
        #pragma unroll
        for (int nb = 0; nb < 2; ++nb) {
            bF[nb][0] = *(const bf16x8*)(base + nb * 2048 + colp0);
            bF[nb][1] = *(const bf16x8*)(base + nb * 2048 + (colp0 ^ 64));
        }
    };
    auto MM = [&](auto MHc, auto NHc, bf16x8 (&bF)[2][2]) {
        constexpr int MH = decltype(MHc)::value;
        constexpr int NH = decltype(NHc)::value;
        __builtin_amdgcn_s_setprio(1);
        #pragma unroll
        for (int mb = 0; mb < 4; ++mb)
            #pragma unroll
            for (int nb = 0; nb < 2; ++nb)
                #pragma unroll
                for (int kk = 0; kk < 2; ++kk)
                    acc[MH * 4 + mb][NH * 2 + nb] = __builtin_amdgcn_mfma_f32_16x16x32_bf16(
                        aF[mb][kk], bF[nb][kk], acc[MH * 4 + mb][NH * 2 + nb], 0, 0, 0);
        __builtin_amdgcn_s_setprio(0);
    };

    auto C0 = std::integral_constant<int, 0>{};
    auto C1 = std::integral_constant<int, 1>{};

    auto ITER = [&](auto LASTc, int t1, int t2, int t3) {
        constexpr bool LAST = decltype(LASTc)::value;
        LDA(0, 0); LDB(b0F, 0, 0);
        STAGE(1, t1, 2); STAGE(1, t1, 3);
        BAR; LGK0; MM(C0, C0, b0F); BAR;
        LDB(b1F, 0, 1);
        STAGE(1, t1, 4); STAGE(1, t1, 5);
        BAR; LGK0; MM(C0, C1, b1F); BAR;
        LDA(0, 1);
        STAGE(1, t1, 6); STAGE(1, t1, 7);
        BAR; LGK0; MM(C1, C1, b1F); BAR;
        if constexpr (!LAST) { STAGE(0, t2, 0); STAGE(0, t2, 1); }
        BAR; MM(C1, C0, b0F);
        if constexpr (LAST) { VMW0; } else { VMW2; }
        BAR;
        LDA(1, 0); LDB(b0F, 1, 0);
        if constexpr (!LAST) { STAGE(0, t2, 2); STAGE(0, t2, 3); }
        BAR; LGK0; MM(C0, C0, b0F); BAR;
        LDB(b1F, 1, 1);
        if constexpr (!LAST) { STAGE(0, t2, 4); STAGE(0, t2, 5); }
        BAR; LGK0; MM(C0, C1, b1F); BAR;
        LDA(1, 1);
        if constexpr (!LAST) { STAGE(0, t2, 6); STAGE(0, t2, 7); }
        BAR; LGK0; MM(C1, C1, b1F); BAR;
        if constexpr (!LAST) {
            STAGE(1, t3, 0); STAGE(1, t3, 1);
            BAR; MM(C1, C0, b0F); VMW2; BAR;
        } else {
            MM(C1, C0, b0F);
        }
    };

    #pragma unroll
    for (int q = 0; q < 8; ++q) STAGE(0, 0, q);
    STAGE(1, 1, 0); STAGE(1, 1, 1);
    VMW2; BAR;

    #pragma unroll 1
    for (int i = 0; i < 7; ++i)
        ITER(std::false_type{}, 2 * i + 1, 2 * i + 2, 2 * i + 3);
    ITER(std::true_type{}, 15, 16, 17);

    const int s    = s0 + (n0 >> 10);
    const int oc   = (n0 & 1023) + wc * 64 + (l & 15);
    float bv[4] = {};
    if constexpr (!RAW) {
        #pragma unroll
        for (int nb = 0; nb < 4; ++nb) bv[nb] = bias[s * NOUT + oc + nb * 16];
    }
    float* outp = out + (size_t)s * NB * NOUT;
    #pragma unroll
    for (int mb = 0; mb < 8; ++mb) {
        #pragma unroll
        for (int i2 = 0; i2 < 4; ++i2) {
            int row = m0 + wr * 128 + mb * 16 + (l >> 4) * 4 + i2;
            float* rp = outp + (size_t)row * NOUT + oc;
            #pragma unroll
            for (int nb = 0; nb < 4; ++nb)
                rp[nb * 16] = acc[mb][nb][i2] + bv[nb];
        }
    }
}

// =====================================================================
// MX-fp8 256x256 8-phase GEMM: out[s,m,o] = y0[m,o] + bias[s,o]
//   + xf8(M,K) . rf8(N=sc*NOUT,K)^T      (e4m3, unit scales)
// Same staging geometry as bf16 kernel: rows are 128 B (256x128 fp8),
// same gload16 units, same T2 swizzle involution, same barrier/vmcnt
// ledger. K-tile = 128 -> 8 tiles -> 4 ITERs. Frags: 32 B/lane (i32x8),
// A: row=l&15, k=(l>>4)*32+j ; B: col=l&15, same k (analog of verified
// 16x16x32 bf16 mapping; mfma_scale 16x16x128, fmtA=fmtB=0 (e4m3),
// scale bytes 127 = 1.0).
// =====================================================================
__launch_bounds__(512, 2)
__global__ void gemm256mx(const unsigned char* __restrict__ xf8,
                          const unsigned char* __restrict__ rf8,
                          const float* __restrict__ y0,
                          const float* __restrict__ bias,
                          float* __restrict__ out, int s0, int nwg) {
    __shared__ __align__(16) char smem[131072];
    const int tid = threadIdx.x;
    const int l   = tid & 63;
    const int w   = tid >> 6;
    const int wr  = w >> 2, wc = w & 3;

    const int b   = blockIdx.x;
    const int q8  = nwg >> 3;
    const int g   = (b & 7) * q8 + (b >> 3);
    const int mi  = g & 15;
    const int ni  = g >> 4;
    const int m0  = mi * 256;
    const int n0  = ni * 256;

    const int srow = l >> 3;
    const int scolb = ((l & 7) ^ srow) * 16;          // BYTES
    const size_t slane = (size_t)srow * NIN + scolb;  // NIN bytes/row (fp8)

    const int rowp = (l & 15) * 128;
    const int c0   = ((l >> 4) * 32) ^ ((l & 7) << 4);
    const int c1   = c0 ^ 16;

    f32x4 acc[8][4] = {};
    i32x8 aF[4], b0F[2], b1F[2];

    const unsigned char* xbase = xf8 + (size_t)m0 * NIN;
    const unsigned char* rbase = rf8 + (size_t)n0 * NIN;

    auto STAGE = [&](int buf, int kt, int q) {
        const int R = (q & 3) * 64 + w * 8;
        const unsigned char* src = ((q < 4) ? xbase : rbase)
                                   + (size_t)R * NIN + kt * 128 + slane;
        char* dst = smem + buf * 65536 + ((q >= 4) ? 32768 : 0) + R * 128;
        gload16(src, dst);
    };
    auto LDA = [&](int buf, int mh) {
        const char* base = smem + buf * 65536 + (wr * 128 + mh * 64) * 128 + rowp;
        #pragma unroll
        for (int mb = 0; mb < 4; ++mb) {
            i32x4 lo = *(const i32x4*)(base + mb * 2048 + c0);
            i32x4 hi = *(const i32x4*)(base + mb * 2048 + c1);
            aF[mb] = __builtin_shufflevector(lo, hi, 0, 1, 2, 3, 4, 5, 6, 7);
        }
    };
    auto LDB = [&](i32x8 (&bF)[2], int buf, int nh) {
        const char* base = smem + buf * 65536 + 32768 + (wc * 64 + nh * 32) * 128 + rowp;
        #pragma unroll
        for (int nb = 0; nb < 2; ++nb) {
            i32x4 lo = *(const i32x4*)(base + nb * 2048 + c0);
            i32x4 hi = *(const i32x4*)(base + nb * 2048 + c1);
            bF[nb] = __builtin_shufflevector(lo, hi, 0, 1, 2, 3, 4, 5, 6, 7);
        }
    };
    auto MM = [&](auto MHc, auto NHc, i32x8 (&bF)[2]) {
        constexpr int MH = decltype(MHc)::value;
        constexpr int NH = decltype(NHc)::value;
        __builtin_amdgcn_s_setprio(1);
        #pragma unroll
        for (int mb = 0; mb < 4; ++mb)
            #pragma unroll
            for (int nb = 0; nb < 2; ++nb)
                acc[MH * 4 + mb][NH * 2 + nb] =
                    __builtin_amdgcn_mfma_scale_f32_16x16x128_f8f6f4(
                        aF[mb], bF[nb], acc[MH * 4 + mb][NH * 2 + nb],
                        0, 0,            // fmt A = fp8 e4m3, fmt B = fp8 e4m3
                        0, 127,          // opsel_a, scale_a (e8m0 127 = 1.0)
                        0, 127);         // opsel_b, scale_b
        __builtin_amdgcn_s_setprio(0);
    };

    auto C0c = std::integral_constant<int, 0>{};
    auto C1c = std::integral_constant<int, 1>{};

    auto ITER = [&](auto LASTc, int t1, int t2, int t3) {
        constexpr bool LAST = decltype(LASTc)::value;
        LDA(0, 0); LDB(b0F, 0, 0);
        STAGE(1, t1, 2); STAGE(1, t1, 3);
        BAR; LGK0; MM(C0c, C0c, b0F); BAR;
        LDB(b1F, 0, 1);
        STAGE(1, t1, 4); STAGE(1, t1, 5);
        BAR; LGK0; MM(C0c, C1c, b1F); BAR;
        LDA(0, 1);
        STAGE(1, t1, 6); STAGE(1, t1, 7);
        BAR; LGK0; MM(C1c, C1c, b1F); BAR;
        if constexpr (!LAST) { STAGE(0, t2, 0); STAGE(0, t2, 1); }
        BAR; MM(C1c, C0c, b0F);
        if constexpr (LAST) { VMW0; } else { VMW2; }
        BAR;
        LDA(1, 0); LDB(b0F, 1, 0);
        if constexpr (!LAST) { STAGE(0, t2, 2); STAGE(0, t2, 3); }
        BAR; LGK0; MM(C0c, C0c, b0F); BAR;
        LDB(b1F, 1, 1);
        if constexpr (!LAST) { STAGE(0, t2, 4); STAGE(0, t2, 5); }
        BAR; LGK0; MM(C0c, C1c, b1F); BAR;
        LDA(1, 1);
        if constexpr (!LAST) { STAGE(0, t2, 6); STAGE(0, t2, 7); }
        BAR; LGK0; MM(C1c, C1c, b1F); BAR;
        if constexpr (!LAST) {
            STAGE(1, t3, 0); STAGE(1, t3, 1);
            BAR; MM(C1c, C0c, b0F); VMW2; BAR;
        } else {
            MM(C1c, C0c, b0F);
        }
    };

    // prologue: tile0 -> buf0 (8), tile1 q0,1 -> buf1 ; vmcnt(2) -> t0 landed
    #pragma unroll
    for (int q = 0; q < 8; ++q) STAGE(0, 0, q);
    STAGE(1, 1, 0); STAGE(1, 1, 1);
    VMW2; BAR;

    // 8 K-tiles of 128 -> 4 ITERs
    #pragma unroll 1
    for (int i = 0; i < 3; ++i)
        ITER(std::false_type{}, 2 * i + 1, 2 * i + 2, 2 * i + 3);
    ITER(std::true_type{}, 7, 8, 9);

    // epilogue: out = acc + y0[row, ocl] + bias[s, ocl]
    const int s   = s0 + (n0 >> 10);
    const int ocl = (n0 & 1023) + wc * 64 + (l & 15);
    float bv[4];
    #pragma unroll
    for (int nb = 0; nb < 4; ++nb) bv[nb] = bias[s * NOUT + ocl + nb * 16];
    float* outp = out + (size_t)s * NB * NOUT;
    #pragma unroll
    for (int mb = 0; mb < 8; ++mb) {
        #pragma unroll
        for (int i2 = 0; i2 < 4; ++i2) {
            int row = m0 + wr * 128 + mb * 16 + (l >> 4) * 4 + i2;
            const float* yr = y0 + (size_t)row * NOUT + ocl;
            float* rp = outp + (size_t)row * NOUT + ocl;
            #pragma unroll
            for (int nb = 0; nb < 4; ++nb)
                rp[nb * 16] = acc[mb][nb][i2] + yr[nb * 16] + bv[nb];
        }
    }
}

// ---- zero-scratch correctness fallback (only if ws_size is tiny) ----
__global__ void fused_fallback(const float* __restrict__ x, const float* __restrict__ wmu,
                               const float* __restrict__ wls, const float* __restrict__ r1,
                               const float* __restrict__ bmu, const float* __restrict__ bls,
                               const float* __restrict__ r2, float* __restrict__ out) {
    __shared__ float Xs[16][64];
    __shared__ float Ws[16][64];
    int b0 = blockIdx.x * 16, o0 = blockIdx.y * 16, s = blockIdx.z;
    int tb = threadIdx.x >> 4, to = threadIdx.x & 15;
    float acc = 0.f;
    for (int k0 = 0; k0 < NIN; k0 += 64) {
        __syncthreads();
        #pragma unroll
        for (int j = 0; j < 4; ++j) {
            int e = j * 256 + threadIdx.x;
            int r = e >> 6, cc = e & 63;
            Xs[r][cc] = x[(size_t)(b0 + r) * NIN + k0 + cc];
            size_t wi = (size_t)(o0 + r) * NIN + k0 + cc;
            Ws[r][cc] = wmu[wi] + __expf(wls[wi]) * r1[(size_t)s * NIN * NOUT + wi];
        }
        __syncthreads();
        for (int k = 0; k < 64; ++k) acc += Xs[tb][k] * Ws[to][k];
    }
    int o = o0 + to;
    out[((size_t)s * NB + b0 + tb) * NOUT + o] = acc + bmu[o] + __expf(bls[o]) * r2[s * NOUT + o];
}

extern "C" void kernel_launch(void* const* d_in, const int* in_sizes, int n_in,
                              void* d_out, int out_size, void* d_ws, size_t ws_size,
                              hipStream_t stream) {
    const float* x   = (const float*)d_in[0];
    const float* wmu = (const float*)d_in[1];
    const float* wls = (const float*)d_in[2];
    const float* bmu = (const float*)d_in[3];
    const float* bls = (const float*)d_in[4];
    const float* r1  = (const float*)d_in[5];
    const float* r2  = (const float*)d_in[6];
    const int S = in_sizes[6] / NOUT;
    float* out = (float*)d_out;

    const size_t xb_b   = (size_t)NB * NIN * 2;       // 8 MB  bf16 x
    const size_t xf8_b  = (size_t)NB * NIN;           // 4 MB  fp8 x
    const size_t wmub_b = (size_t)NOUT * NIN * 2;     // 2 MB  bf16 w_mu
    const size_t y0_b   = (size_t)NB * NOUT * 4;      // 16 MB f32 y0
    const size_t bias_b = (size_t)S * NOUT * 4;
    const size_t per_s  = (size_t)NOUT * NIN;         // 1 MB fp8 per sample
    const size_t base_b = xb_b + xf8_b + wmub_b + y0_b + bias_b;

    if (ws_size < base_b + per_s) {
        dim3 gg(NB / 16, NOUT / 16, S);
        fused_fallback<<<gg, 256, 0, stream>>>(x, wmu, wls, r1, bmu, bls, r2, out);
        return;
    }

    char* ws = (char*)d_ws;
    unsigned short* xb   = (unsigned short*)ws;
    unsigned char*  xf8  = (unsigned char*)(ws + xb_b);
    unsigned short* wmub = (unsigned short*)(ws + xb_b + xf8_b);
    float*          y0   = (float*)(ws + xb_b + xf8_b + wmub_b);
    float*          bias = (float*)(ws + xb_b + xf8_b + wmub_b + y0_b);
    unsigned char*  rf8  = (unsigned char*)(ws + base_b);

    int SC = (int)((ws_size - base_b) / per_s);
    if (SC > S) SC = S;

    cvt_x_kernel<<<NB * NIN / 1024, 256, 0, stream>>>(x, xb);
    cvt_x_kernel<<<NOUT * NIN / 1024, 256, 0, stream>>>(wmu, wmub);
    cvt_x_fp8<<<NB * NIN / 1024, 256, 0, stream>>>(x, (unsigned int*)xf8);
    bias_kernel<<<(S * NOUT + 255) / 256, 256, 0, stream>>>(bmu, bls, r2, bias, S * NOUT);

    // y0 = x . w_mu^T   (bf16, 64 blocks)
    gemm256<true><<<64, 512, 0, stream>>>(xb, wmub, nullptr, y0, 0, 64);

    for (int s0 = 0; s0 < S; s0 += SC) {
        int sc = (S - s0 < SC) ? (S - s0) : SC;
        cvt_r1_fp8<<<sc * (NOUT * NIN / 1024), 256, 0, stream>>>(wls, r1, (unsigned int*)rf8, s0);
        int nwg = 64 * sc;   // 16 mi x (sc*4 ni), always % 8 == 0
        gemm256mx<<<nwg, 512, 0, stream>>>(xf8, rf8, y0, bias, out, s0, nwg);
    }
}

// Round 7
// 822.061 us; speedup vs baseline: 1.2006x; 1.2006x over previous
//
#include <hip/hip_runtime.h>
#include <hip/hip_bf16.h>
#include <hip/hip_fp8.h>
#include <stdint.h>
#include <type_traits>

#define NIN  1024
#define NOUT 1024
#define NB   4096   // batch

typedef float f32x4  __attribute__((ext_vector_type(4)));
typedef float f32x16 __attribute__((ext_vector_type(16)));
typedef __bf16 bf16x8 __attribute__((ext_vector_type(8)));
typedef int   i32x4 __attribute__((ext_vector_type(4)));
typedef int   i32x8 __attribute__((ext_vector_type(8)));

typedef const __attribute__((address_space(1))) unsigned int* gp1_t;
typedef __attribute__((address_space(3))) unsigned int* lp3_t;

__device__ __forceinline__ void gload16(const void* g, void* l) {
    __builtin_amdgcn_global_load_lds((gp1_t)g, (lp3_t)l, 16, 0, 0);
}

__device__ __forceinline__ unsigned short f2bf(float f) {
    __bf16 h = (__bf16)f;
    return __builtin_bit_cast(unsigned short, h);
}

// pack 4 floats -> 4 e4m3fn bytes
__device__ __forceinline__ unsigned int pk4_fp8(float a, float b, float c, float d) {
#if __has_builtin(__builtin_amdgcn_cvt_pk_fp8_f32)
    int p = __builtin_amdgcn_cvt_pk_fp8_f32(a, b, 0, false);
    p = __builtin_amdgcn_cvt_pk_fp8_f32(c, d, p, true);
    return (unsigned int)p;
#else
    __hip_fp8_e4m3 qa(a), qb(b), qc(c), qd(d);
    return (unsigned int)qa.__x | ((unsigned int)qb.__x << 8) |
           ((unsigned int)qc.__x << 16) | ((unsigned int)qd.__x << 24);
#endif
}

#define BAR   __builtin_amdgcn_s_barrier()
#define LGK0  do { asm volatile("s_waitcnt lgkmcnt(0)" ::: "memory"); __builtin_amdgcn_sched_barrier(0); } while (0)
#define VMW12 do { asm volatile("s_waitcnt vmcnt(12)" ::: "memory"); __builtin_amdgcn_sched_barrier(0); } while (0)
#define VMW8  do { asm volatile("s_waitcnt vmcnt(8)"  ::: "memory"); __builtin_amdgcn_sched_barrier(0); } while (0)
#define VMW4  do { asm volatile("s_waitcnt vmcnt(4)"  ::: "memory"); __builtin_amdgcn_sched_barrier(0); } while (0)
#define VMW2  do { asm volatile("s_waitcnt vmcnt(2)"  ::: "memory"); __builtin_amdgcn_sched_barrier(0); } while (0)
#define VMW0  do { asm volatile("s_waitcnt vmcnt(0)"  ::: "memory"); __builtin_amdgcn_sched_barrier(0); } while (0)

// ---- prep: f32 -> bf16 ----
__global__ void cvt_x_kernel(const float* __restrict__ x, unsigned short* __restrict__ xb) {
    int i = blockIdx.x * blockDim.x + threadIdx.x;
    f32x4 v = reinterpret_cast<const f32x4*>(x)[i];
    ushort4 o;
    o.x = f2bf(v.x); o.y = f2bf(v.y); o.z = f2bf(v.z); o.w = f2bf(v.w);
    reinterpret_cast<ushort4*>(xb)[i] = o;
}

// ---- prep: x -> fp8 e4m3 ----
__global__ void cvt_x_fp8(const float* __restrict__ x, unsigned int* __restrict__ xf8) {
    int i = blockIdx.x * blockDim.x + threadIdx.x;
    f32x4 v = reinterpret_cast<const f32x4*>(x)[i];
    xf8[i] = pk4_fp8(v.x, v.y, v.z, v.w);
}

// ---- prep: rf8[c,o,i] = fp8( exp(wls[o,i]) * r1[s0+c,o,i] ) ----
__global__ void cvt_r1_fp8(const float* __restrict__ wls, const float* __restrict__ r1,
                           unsigned int* __restrict__ rf8, int s0) {
    int idx = blockIdx.x * blockDim.x + threadIdx.x;
    int i4 = idx & 262143;
    int c  = idx >> 18;
    f32x4 ls = reinterpret_cast<const f32x4*>(wls)[i4];
    const f32x4* rp = reinterpret_cast<const f32x4*>(r1 + ((size_t)(s0 + c) << 20));
    f32x4 r = rp[i4];
    rf8[idx] = pk4_fp8(__expf(ls.x) * r.x, __expf(ls.y) * r.y,
                       __expf(ls.z) * r.z, __expf(ls.w) * r.w);
}

// ---- prep: bias[s,o] = b_mu[o] + exp(b_ls[o]) * r2[s,o] ----
__global__ void bias_kernel(const float* __restrict__ bmu, const float* __restrict__ bls,
                            const float* __restrict__ r2, float* __restrict__ bias, int total) {
    int i = blockIdx.x * blockDim.x + threadIdx.x;
    if (i < total) {
        int o = i & (NOUT - 1);
        bias[i] = bmu[o] + __expf(bls[o]) * r2[i];
    }
}

// =====================================================================
// bf16 256x256 8-phase GEMM (r2-proven schedule), used for y0 = x.w_mu^T
// =====================================================================
__launch_bounds__(512, 2)
__global__ void gemm256(const unsigned short* __restrict__ xb,
                        const unsigned short* __restrict__ wb,
                        float* __restrict__ out, int nwg) {
    __shared__ __align__(16) char smem[131072];
    const int tid = threadIdx.x;
    const int l   = tid & 63;
    const int w   = tid >> 6;
    const int wr  = w >> 2, wc = w & 3;

    const int b   = blockIdx.x;
    const int q8  = nwg >> 3;
    const int g   = (b & 7) * q8 + (b >> 3);
    const int mi  = g & 15;
    const int ni  = g >> 4;
    const int m0  = mi * 256;
    const int n0  = ni * 256;

    const int srow = l >> 3;
    const int scol = ((l & 7) ^ srow) * 8;
    const size_t slane = (size_t)srow * NIN + scol;

    const int rowp  = (l & 15) * 128;
    const int colp0 = ((l >> 4) ^ (l & 7)) << 4;

    f32x4 acc[8][4] = {};
    bf16x8 aF[4][2], b0F[2][2], b1F[2][2];

    const unsigned short* xbase = xb + (size_t)m0 * NIN;
    const unsigned short* wbase = wb + (size_t)n0 * NIN;

    auto STAGE = [&](int buf, int kt, int q) {
        const int R = (q & 3) * 64 + w * 8;
        const unsigned short* src = ((q < 4) ? xbase : wbase)
                                    + (size_t)R * NIN + kt * 64 + slane;
        char* dst = smem + buf * 65536 + ((q >= 4) ? 32768 : 0) + R * 128;
        gload16(src, dst);
    };
    auto LDA = [&](int buf, int mh) {
        const char* base = smem + buf * 65536 + (wr * 128 + mh * 64) * 128 + rowp;
        #pragma unroll
        for (int mb = 0; mb < 4; ++mb) {
            aF[mb][0] = *(const bf16x8*)(base + mb * 2048 + colp0);
            aF[mb][1] = *(const bf16x8*)(base + mb * 2048 + (colp0 ^ 64));
        }
    };
    auto LDB = [&](bf16x8 (&bF)[2][2], int buf, int nh) {
        const char* base = smem + buf * 65536 + 32768 + (wc * 64 + nh * 32) * 128 + rowp;
        #pragma unroll
        for (int nb = 0; nb < 2; ++nb) {
            bF[nb][0] = *(const bf16x8*)(base + nb * 2048 + colp0);
            bF[nb][1] = *(const bf16x8*)(base + nb * 2048 + (colp0 ^ 64));
        }
    };
    auto MM = [&](auto MHc, auto NHc, bf16x8 (&bF)[2][2]) {
        constexpr int MH = decltype(MHc)::value;
        constexpr int NH = decltype(NHc)::value;
        __builtin_amdgcn_s_setprio(1);
        #pragma unroll
        for (int mb = 0; mb < 4; ++mb)
            #pragma unroll
            for (int nb = 0; nb < 2; ++nb)
                #pragma unroll
                for (int kk = 0; kk < 2; ++kk)
                    acc[MH * 4 + mb][NH * 2 + nb] = __builtin_amdgcn_mfma_f32_16x16x32_bf16(
                        aF[mb][kk], bF[nb][kk], acc[MH * 4 + mb][NH * 2 + nb], 0, 0, 0);
        __builtin_amdgcn_s_setprio(0);
    };

    auto C0 = std::integral_constant<int, 0>{};
    auto C1 = std::integral_constant<int, 1>{};

    auto ITER = [&](auto LASTc, int t1, int t2, int t3) {
        constexpr bool LAST = decltype(LASTc)::value;
        LDA(0, 0); LDB(b0F, 0, 0);
        STAGE(1, t1, 2); STAGE(1, t1, 3);
        BAR; LGK0; MM(C0, C0, b0F); BAR;
        LDB(b1F, 0, 1);
        STAGE(1, t1, 4); STAGE(1, t1, 5);
        BAR; LGK0; MM(C0, C1, b1F); BAR;
        LDA(0, 1);
        STAGE(1, t1, 6); STAGE(1, t1, 7);
        BAR; LGK0; MM(C1, C1, b1F); BAR;
        if constexpr (!LAST) { STAGE(0, t2, 0); STAGE(0, t2, 1); }
        BAR; MM(C1, C0, b0F);
        if constexpr (LAST) { VMW0; } else { VMW2; }
        BAR;
        LDA(1, 0); LDB(b0F, 1, 0);
        if constexpr (!LAST) { STAGE(0, t2, 2); STAGE(0, t2, 3); }
        BAR; LGK0; MM(C0, C0, b0F); BAR;
        LDB(b1F, 1, 1);
        if constexpr (!LAST) { STAGE(0, t2, 4); STAGE(0, t2, 5); }
        BAR; LGK0; MM(C0, C1, b1F); BAR;
        LDA(1, 1);
        if constexpr (!LAST) { STAGE(0, t2, 6); STAGE(0, t2, 7); }
        BAR; LGK0; MM(C1, C1, b1F); BAR;
        if constexpr (!LAST) {
            STAGE(1, t3, 0); STAGE(1, t3, 1);
            BAR; MM(C1, C0, b0F); VMW2; BAR;
        } else {
            MM(C1, C0, b0F);
        }
    };

    #pragma unroll
    for (int q = 0; q < 8; ++q) STAGE(0, 0, q);
    STAGE(1, 1, 0); STAGE(1, 1, 1);
    VMW2; BAR;

    #pragma unroll 1
    for (int i = 0; i < 7; ++i)
        ITER(std::false_type{}, 2 * i + 1, 2 * i + 2, 2 * i + 3);
    ITER(std::true_type{}, 15, 16, 17);

    const int oc = n0 + wc * 64 + (l & 15);
    float* outp = out;
    #pragma unroll
    for (int mb = 0; mb < 8; ++mb) {
        #pragma unroll
        for (int i2 = 0; i2 < 4; ++i2) {
            int row = m0 + wr * 128 + mb * 16 + (l >> 4) * 4 + i2;
            float* rp = outp + (size_t)row * NOUT + oc;
            #pragma unroll
            for (int nb = 0; nb < 4; ++nb)
                rp[nb * 16] = acc[mb][nb][i2];
        }
    }
}

// =====================================================================
// MX-fp8 256x256 GEMM v2: 32x32x64 mfma_scale (2x FLOP per LDS byte),
// BK=64 (64B rows), 4-buffer LDS ring (4 x 32KB), 1 phase per K-tile:
//   { STAGE(t+3): 4 gload16 ; vmcnt(12) ; BAR ; 12 ds_read_b128 ;
//     lgkmcnt(0) ; 8 MFMA ; BAR }
// vmcnt ledger: after staging t+3, outstanding = tiles t+1..t+3 = 12 ->
// vmcnt(12) proves tile t landed, with 3 phases of slack (>= HBM lat).
// Buffer (t+3)&3 == (t-1)&3, whose reads finished before the previous
// closing BAR -> no overwrite race. Swizzle: chunk ^= (row&3) on 16B
// chunks within each 64B row (2-way max per 8-lane group = free).
// =====================================================================
__launch_bounds__(512, 2)
__global__ void gemm256mx(const unsigned char* __restrict__ xf8,
                          const unsigned char* __restrict__ rf8,
                          const float* __restrict__ y0,
                          const float* __restrict__ bias,
                          float* __restrict__ out, int s0, int nwg) {
    __shared__ __align__(16) char smem[131072];
    const int tid = threadIdx.x;
    const int l   = tid & 63;
    const int w   = tid >> 6;
    const int wr  = w >> 2, wc = w & 3;   // 2M x 4N waves, wave tile 128x64

    const int b   = blockIdx.x;
    const int q8  = nwg >> 3;
    const int g   = (b & 7) * q8 + (b >> 3);
    const int mi  = g & 15;
    const int ni  = g >> 4;
    const int m0  = mi * 256;
    const int n0  = ni * 256;

    // staging: 4 loads/thread/tile. Unit q: q0=A rows0-127, q1=A rows128-255,
    // q2=B rows0-127, q3=B rows128-255. Thread covers row tid>>2, chunk tid&3.
    const int srow_u = tid >> 2;                  // 0..127
    const int schnk  = (tid & 3) ^ (srow_u & 3);  // source logical chunk (involution)
    const int dlin   = w * 1024 + l * 16;         // == (tid>>2)*64 + (tid&3)*16

    // frag-read geometry (32x32x64): row = l&31 (+tile offsets), k-group (l>>5)
    const int arow = l & 31;
    const int kg   = (l >> 5) * 2;          // 16B-chunk pair base
    const int ksw  = l & 3;                 // swizzle key (== row&3)

    f32x16 acc[4][2] = {};
    i32x8 aF[4], bF[2];

    const unsigned char* xbase = xf8 + (size_t)m0 * NIN;
    const unsigned char* rbase = rf8 + (size_t)n0 * NIN;

    auto STAGE_TILE = [&](int t) {
        char* base = smem + (t & 3) * 32768;
        #pragma unroll
        for (int q = 0; q < 4; ++q) {
            const unsigned char* panel = (q < 2) ? xbase : rbase;
            const unsigned char* src = panel + (size_t)((q & 1) * 128 + srow_u) * NIN
                                       + t * 64 + schnk * 16;
            char* dst = base + (q >= 2 ? 16384 : 0) + (q & 1) * 8192 + dlin;
            gload16(src, dst);
        }
    };

    auto LDFRAGS = [&](int bsel) {
        const char* Ab = smem + bsel * 32768;
        const char* Bb = Ab + 16384;
        #pragma unroll
        for (int mb = 0; mb < 4; ++mb) {
            const char* rb = Ab + (wr * 128 + mb * 32 + arow) * 64;
            i32x4 lo = *(const i32x4*)(rb + ((kg + 0) ^ ksw) * 16);
            i32x4 hi = *(const i32x4*)(rb + ((kg + 1) ^ ksw) * 16);
            aF[mb] = __builtin_shufflevector(lo, hi, 0, 1, 2, 3, 4, 5, 6, 7);
        }
        #pragma unroll
        for (int nb = 0; nb < 2; ++nb) {
            const char* rb = Bb + (wc * 64 + nb * 32 + arow) * 64;
            i32x4 lo = *(const i32x4*)(rb + ((kg + 0) ^ ksw) * 16);
            i32x4 hi = *(const i32x4*)(rb + ((kg + 1) ^ ksw) * 16);
            bF[nb] = __builtin_shufflevector(lo, hi, 0, 1, 2, 3, 4, 5, 6, 7);
        }
    };

    auto MM = [&]() {
        __builtin_amdgcn_s_setprio(1);
        #pragma unroll
        for (int mb = 0; mb < 4; ++mb)
            #pragma unroll
            for (int nb = 0; nb < 2; ++nb)
                acc[mb][nb] = __builtin_amdgcn_mfma_scale_f32_32x32x64_f8f6f4(
                    aF[mb], bF[nb], acc[mb][nb],
                    0, 0,        // fmt A = fp8 e4m3, fmt B = fp8 e4m3
                    0, 127,      // opsel_a, scale_a (e8m0 1.0)
                    0, 127);     // opsel_b, scale_b
        __builtin_amdgcn_s_setprio(0);
    };

    // prologue: tiles 0,1,2 in flight
    STAGE_TILE(0); STAGE_TILE(1); STAGE_TILE(2);

    // phases 0..12: stage p+3, gate tile p with vmcnt(12)
    #pragma unroll 1
    for (int p = 0; p < 13; ++p) {
        STAGE_TILE(p + 3);
        VMW12;
        BAR; LDFRAGS(p & 3); LGK0; MM(); BAR;
    }
    // tail phases 13,14,15: gates 8/4/0
    VMW8; BAR; LDFRAGS(1); LGK0; MM(); BAR;
    VMW4; BAR; LDFRAGS(2); LGK0; MM(); BAR;
    VMW0; BAR; LDFRAGS(3); LGK0; MM();

    // epilogue: out = acc + y0 + bias. 32x32 C/D: col=l&31,
    // row = (reg&3) + 8*(reg>>2) + 4*(l>>5)
    const int s    = s0 + (n0 >> 10);
    const int ocl0 = (n0 & 1023) + wc * 64 + (l & 31);
    float bv[2];
    #pragma unroll
    for (int nb = 0; nb < 2; ++nb) bv[nb] = bias[s * NOUT + ocl0 + nb * 32];
    float* outp = out + (size_t)s * NB * NOUT;
    const int rbase0 = m0 + wr * 128 + 4 * (l >> 5);
    #pragma unroll
    for (int mb = 0; mb < 4; ++mb) {
        #pragma unroll
        for (int nb = 0; nb < 2; ++nb) {
            const int colg = ocl0 + nb * 32;
            #pragma unroll
            for (int r = 0; r < 16; ++r) {
                int row = rbase0 + mb * 32 + (r & 3) + 8 * (r >> 2);
                size_t off = (size_t)row * NOUT + colg;   // index within one S-slice
                outp[off] = acc[mb][nb][r] + y0[off] + bv[nb];  // y0 is [NB][NOUT]: same off
            }
        }
    }
}

// ---- zero-scratch correctness fallback (only if ws_size is tiny) ----
__global__ void fused_fallback(const float* __restrict__ x, const float* __restrict__ wmu,
                               const float* __restrict__ wls, const float* __restrict__ r1,
                               const float* __restrict__ bmu, const float* __restrict__ bls,
                               const float* __restrict__ r2, float* __restrict__ out) {
    __shared__ float Xs[16][64];
    __shared__ float Ws[16][64];
    int b0 = blockIdx.x * 16, o0 = blockIdx.y * 16, s = blockIdx.z;
    int tb = threadIdx.x >> 4, to = threadIdx.x & 15;
    float acc = 0.f;
    for (int k0 = 0; k0 < NIN; k0 += 64) {
        __syncthreads();
        #pragma unroll
        for (int j = 0; j < 4; ++j) {
            int e = j * 256 + threadIdx.x;
            int r = e >> 6, cc = e & 63;
            Xs[r][cc] = x[(size_t)(b0 + r) * NIN + k0 + cc];
            size_t wi = (size_t)(o0 + r) * NIN + k0 + cc;
            Ws[r][cc] = wmu[wi] + __expf(wls[wi]) * r1[(size_t)s * NIN * NOUT + wi];
        }
        __syncthreads();
        for (int k = 0; k < 64; ++k) acc += Xs[tb][k] * Ws[to][k];
    }
    int o = o0 + to;
    out[((size_t)s * NB + b0 + tb) * NOUT + o] = acc + bmu[o] + __expf(bls[o]) * r2[s * NOUT + o];
}

extern "C" void kernel_launch(void* const* d_in, const int* in_sizes, int n_in,
                              void* d_out, int out_size, void* d_ws, size_t ws_size,
                              hipStream_t stream) {
    const float* x   = (const float*)d_in[0];
    const float* wmu = (const float*)d_in[1];
    const float* wls = (const float*)d_in[2];
    const float* bmu = (const float*)d_in[3];
    const float* bls = (const float*)d_in[4];
    const float* r1  = (const float*)d_in[5];
    const float* r2  = (const float*)d_in[6];
    const int S = in_sizes[6] / NOUT;
    float* out = (float*)d_out;

    const size_t xb_b   = (size_t)NB * NIN * 2;       // 8 MB  bf16 x
    const size_t xf8_b  = (size_t)NB * NIN;           // 4 MB  fp8 x
    const size_t wmub_b = (size_t)NOUT * NIN * 2;     // 2 MB  bf16 w_mu
    const size_t y0_b   = (size_t)NB * NOUT * 4;      // 16 MB f32 y0
    const size_t bias_b = (size_t)S * NOUT * 4;
    const size_t per_s  = (size_t)NOUT * NIN;         // 1 MB fp8 per sample
    const size_t base_b = xb_b + xf8_b + wmub_b + y0_b + bias_b;

    if (ws_size < base_b + per_s) {
        dim3 gg(NB / 16, NOUT / 16, S);
        fused_fallback<<<gg, 256, 0, stream>>>(x, wmu, wls, r1, bmu, bls, r2, out);
        return;
    }

    char* ws = (char*)d_ws;
    unsigned short* xb   = (unsigned short*)ws;
    unsigned char*  xf8  = (unsigned char*)(ws + xb_b);
    unsigned short* wmub = (unsigned short*)(ws + xb_b + xf8_b);
    float*          y0   = (float*)(ws + xb_b + xf8_b + wmub_b);
    float*          bias = (float*)(ws + xb_b + xf8_b + wmub_b + y0_b);
    unsigned char*  rf8  = (unsigned char*)(ws + base_b);

    int SC = (int)((ws_size - base_b) / per_s);
    if (SC > S) SC = S;

    cvt_x_kernel<<<NB * NIN / 1024, 256, 0, stream>>>(x, xb);
    cvt_x_kernel<<<NOUT * NIN / 1024, 256, 0, stream>>>(wmu, wmub);
    cvt_x_fp8<<<NB * NIN / 1024, 256, 0, stream>>>(x, (unsigned int*)xf8);
    bias_kernel<<<(S * NOUT + 255) / 256, 256, 0, stream>>>(bmu, bls, r2, bias, S * NOUT);

    // y0 = x . w_mu^T   (bf16, 64 blocks)
    gemm256<<<64, 512, 0, stream>>>(xb, wmub, y0, 64);

    for (int s0 = 0; s0 < S; s0 += SC) {
        int sc = (S - s0 < SC) ? (S - s0) : SC;
        cvt_r1_fp8<<<sc * (NOUT * NIN / 1024), 256, 0, stream>>>(wls, r1, (unsigned int*)rf8, s0);
        int nwg = 64 * sc;
        gemm256mx<<<nwg, 512, 0, stream>>>(xf8, rf8, y0, bias, out, s0, nwg);
    }
}

// Round 8
// 768.431 us; speedup vs baseline: 1.2844x; 1.0698x over previous
//
#include <hip/hip_runtime.h>
#include <hip/hip_bf16.h>
#include <hip/hip_fp8.h>
#include <stdint.h>
#include <type_traits>

#define NIN  1024
#define NOUT 1024
#define NB   4096   // batch

typedef float f32x4  __attribute__((ext_vector_type(4)));
typedef float f32x16 __attribute__((ext_vector_type(16)));
typedef __bf16 bf16x8 __attribute__((ext_vector_type(8)));
typedef int   i32x4 __attribute__((ext_vector_type(4)));
typedef int   i32x8 __attribute__((ext_vector_type(8)));

typedef const __attribute__((address_space(1))) unsigned int* gp1_t;
typedef __attribute__((address_space(3))) unsigned int* lp3_t;

__device__ __forceinline__ void gload16(const void* g, void* l) {
    __builtin_amdgcn_global_load_lds((gp1_t)g, (lp3_t)l, 16, 0, 0);
}

__device__ __forceinline__ unsigned short f2bf(float f) {
    __bf16 h = (__bf16)f;
    return __builtin_bit_cast(unsigned short, h);
}

// pack 4 floats -> 4 e4m3fn bytes
__device__ __forceinline__ unsigned int pk4_fp8(float a, float b, float c, float d) {
#if __has_builtin(__builtin_amdgcn_cvt_pk_fp8_f32)
    int p = __builtin_amdgcn_cvt_pk_fp8_f32(a, b, 0, false);
    p = __builtin_amdgcn_cvt_pk_fp8_f32(c, d, p, true);
    return (unsigned int)p;
#else
    __hip_fp8_e4m3 qa(a), qb(b), qc(c), qd(d);
    return (unsigned int)qa.__x | ((unsigned int)qb.__x << 8) |
           ((unsigned int)qc.__x << 16) | ((unsigned int)qd.__x << 24);
#endif
}

#define BAR   __builtin_amdgcn_s_barrier()
#define LGK0  do { asm volatile("s_waitcnt lgkmcnt(0)" ::: "memory"); __builtin_amdgcn_sched_barrier(0); } while (0)
#define VMW2  do { asm volatile("s_waitcnt vmcnt(2)"  ::: "memory"); __builtin_amdgcn_sched_barrier(0); } while (0)
#define VMW0  do { asm volatile("s_waitcnt vmcnt(0)"  ::: "memory"); __builtin_amdgcn_sched_barrier(0); } while (0)

// ---- prep: f32 -> bf16 ----
__global__ void cvt_x_kernel(const float* __restrict__ x, unsigned short* __restrict__ xb) {
    int i = blockIdx.x * blockDim.x + threadIdx.x;
    f32x4 v = reinterpret_cast<const f32x4*>(x)[i];
    ushort4 o;
    o.x = f2bf(v.x); o.y = f2bf(v.y); o.z = f2bf(v.z); o.w = f2bf(v.w);
    reinterpret_cast<ushort4*>(xb)[i] = o;
}

// ---- prep: x -> fp8 e4m3 ----
__global__ void cvt_x_fp8(const float* __restrict__ x, unsigned int* __restrict__ xf8) {
    int i = blockIdx.x * blockDim.x + threadIdx.x;
    f32x4 v = reinterpret_cast<const f32x4*>(x)[i];
    xf8[i] = pk4_fp8(v.x, v.y, v.z, v.w);
}

// ---- prep: rf8[c,o,i] = fp8( exp(wls[o,i]) * r1[s0+c,o,i] ) ----
__global__ void cvt_r1_fp8(const float* __restrict__ wls, const float* __restrict__ r1,
                           unsigned int* __restrict__ rf8, int s0) {
    int idx = blockIdx.x * blockDim.x + threadIdx.x;
    int i4 = idx & 262143;
    int c  = idx >> 18;
    f32x4 ls = reinterpret_cast<const f32x4*>(wls)[i4];
    const f32x4* rp = reinterpret_cast<const f32x4*>(r1 + ((size_t)(s0 + c) << 20));
    f32x4 r = rp[i4];
    rf8[idx] = pk4_fp8(__expf(ls.x) * r.x, __expf(ls.y) * r.y,
                       __expf(ls.z) * r.z, __expf(ls.w) * r.w);
}

// ---- prep: bias[s,o] = b_mu[o] + exp(b_ls[o]) * r2[s,o] ----
__global__ void bias_kernel(const float* __restrict__ bmu, const float* __restrict__ bls,
                            const float* __restrict__ r2, float* __restrict__ bias, int total) {
    int i = blockIdx.x * blockDim.x + threadIdx.x;
    if (i < total) {
        int o = i & (NOUT - 1);
        bias[i] = bmu[o] + __expf(bls[o]) * r2[i];
    }
}

// =====================================================================
// bf16 256x256 8-phase GEMM (r2-proven schedule), used for y0 = x.w_mu^T
// =====================================================================
__launch_bounds__(512, 2)
__global__ void gemm256(const unsigned short* __restrict__ xb,
                        const unsigned short* __restrict__ wb,
                        float* __restrict__ out, int nwg) {
    __shared__ __align__(16) char smem[131072];
    const int tid = threadIdx.x;
    const int l   = tid & 63;
    const int w   = tid >> 6;
    const int wr  = w >> 2, wc = w & 3;

    const int b   = blockIdx.x;
    const int q8  = nwg >> 3;
    const int g   = (b & 7) * q8 + (b >> 3);
    const int mi  = g & 15;
    const int ni  = g >> 4;
    const int m0  = mi * 256;
    const int n0  = ni * 256;

    const int srow = l >> 3;
    const int scol = ((l & 7) ^ srow) * 8;
    const size_t slane = (size_t)srow * NIN + scol;

    const int rowp  = (l & 15) * 128;
    const int colp0 = ((l >> 4) ^ (l & 7)) << 4;

    f32x4 acc[8][4] = {};
    bf16x8 aF[4][2], b0F[2][2], b1F[2][2];

    const unsigned short* xbase = xb + (size_t)m0 * NIN;
    const unsigned short* wbase = wb + (size_t)n0 * NIN;

    auto STAGE = [&](int buf, int kt, int q) {
        const int R = (q & 3) * 64 + w * 8;
        const unsigned short* src = ((q < 4) ? xbase : wbase)
                                    + (size_t)R * NIN + kt * 64 + slane;
        char* dst = smem + buf * 65536 + ((q >= 4) ? 32768 : 0) + R * 128;
        gload16(src, dst);
    };
    auto LDA = [&](int buf, int mh) {
        const char* base = smem + buf * 65536 + (wr * 128 + mh * 64) * 128 + rowp;
        #pragma unroll
        for (int mb = 0; mb < 4; ++mb) {
            aF[mb][0] = *(const bf16x8*)(base + mb * 2048 + colp0);
            aF[mb][1] = *(const bf16x8*)(base + mb * 2048 + (colp0 ^ 64));
        }
    };
    auto LDB = [&](bf16x8 (&bF)[2][2], int buf, int nh) {
        const char* base = smem + buf * 65536 + 32768 + (wc * 64 + nh * 32) * 128 + rowp;
        #pragma unroll
        for (int nb = 0; nb < 2; ++nb) {
            bF[nb][0] = *(const bf16x8*)(base + nb * 2048 + colp0);
            bF[nb][1] = *(const bf16x8*)(base + nb * 2048 + (colp0 ^ 64));
        }
    };
    auto MM = [&](auto MHc, auto NHc, bf16x8 (&bF)[2][2]) {
        constexpr int MH = decltype(MHc)::value;
        constexpr int NH = decltype(NHc)::value;
        __builtin_amdgcn_s_setprio(1);
        #pragma unroll
        for (int mb = 0; mb < 4; ++mb)
            #pragma unroll
            for (int nb = 0; nb < 2; ++nb)
                #pragma unroll
                for (int kk = 0; kk < 2; ++kk)
                    acc[MH * 4 + mb][NH * 2 + nb] = __builtin_amdgcn_mfma_f32_16x16x32_bf16(
                        aF[mb][kk], bF[nb][kk], acc[MH * 4 + mb][NH * 2 + nb], 0, 0, 0);
        __builtin_amdgcn_s_setprio(0);
    };

    auto C0 = std::integral_constant<int, 0>{};
    auto C1 = std::integral_constant<int, 1>{};

    auto ITER = [&](auto LASTc, int t1, int t2, int t3) {
        constexpr bool LAST = decltype(LASTc)::value;
        LDA(0, 0); LDB(b0F, 0, 0);
        STAGE(1, t1, 2); STAGE(1, t1, 3);
        BAR; LGK0; MM(C0, C0, b0F); BAR;
        LDB(b1F, 0, 1);
        STAGE(1, t1, 4); STAGE(1, t1, 5);
        BAR; LGK0; MM(C0, C1, b1F); BAR;
        LDA(0, 1);
        STAGE(1, t1, 6); STAGE(1, t1, 7);
        BAR; LGK0; MM(C1, C1, b1F); BAR;
        if constexpr (!LAST) { STAGE(0, t2, 0); STAGE(0, t2, 1); }
        BAR; MM(C1, C0, b0F);
        if constexpr (LAST) { VMW0; } else { VMW2; }
        BAR;
        LDA(1, 0); LDB(b0F, 1, 0);
        if constexpr (!LAST) { STAGE(0, t2, 2); STAGE(0, t2, 3); }
        BAR; LGK0; MM(C0, C0, b0F); BAR;
        LDB(b1F, 1, 1);
        if constexpr (!LAST) { STAGE(0, t2, 4); STAGE(0, t2, 5); }
        BAR; LGK0; MM(C0, C1, b1F); BAR;
        LDA(1, 1);
        if constexpr (!LAST) { STAGE(0, t2, 6); STAGE(0, t2, 7); }
        BAR; LGK0; MM(C1, C1, b1F); BAR;
        if constexpr (!LAST) {
            STAGE(1, t3, 0); STAGE(1, t3, 1);
            BAR; MM(C1, C0, b0F); VMW2; BAR;
        } else {
            MM(C1, C0, b0F);
        }
    };

    #pragma unroll
    for (int q = 0; q < 8; ++q) STAGE(0, 0, q);
    STAGE(1, 1, 0); STAGE(1, 1, 1);
    VMW2; BAR;

    #pragma unroll 1
    for (int i = 0; i < 7; ++i)
        ITER(std::false_type{}, 2 * i + 1, 2 * i + 2, 2 * i + 3);
    ITER(std::true_type{}, 15, 16, 17);

    const int oc = n0 + wc * 64 + (l & 15);
    float* outp = out;
    #pragma unroll
    for (int mb = 0; mb < 8; ++mb) {
        #pragma unroll
        for (int i2 = 0; i2 < 4; ++i2) {
            int row = m0 + wr * 128 + mb * 16 + (l >> 4) * 4 + i2;
            float* rp = outp + (size_t)row * NOUT + oc;
            #pragma unroll
            for (int nb = 0; nb < 4; ++nb)
                rp[nb * 16] = acc[mb][nb][i2];
        }
    }
}

// =====================================================================
// MX-fp8 256x256 GEMM v3: 32x32x64 mfma_scale on the r2-PROVEN memory
// structure. BK = 128 BYTES (128-B LDS rows, zero-conflict-verified
// swizzle), double-buffered 2 x 64KB, r2's exact 8-phase / 2-barrier /
// vmcnt(2) schedule. Per K-tile (K=128): per wave 16 b128 A-reads +
// 8 b128 B-reads, 16 MFMA (4 per phase). 8 K-tiles -> 4 ITERs.
// Store swizzle: phys chunk = logical chunk ^ (row&7) (via pre-swizzled
// global source); read: chunk c of row r at phys (c ^ (r&7)), r&7==l&7.
// =====================================================================
__launch_bounds__(512, 2)
__global__ void gemm256mx(const unsigned char* __restrict__ xf8,
                          const unsigned char* __restrict__ rf8,
                          const float* __restrict__ y0,
                          const float* __restrict__ bias,
                          float* __restrict__ out, int s0, int nwg) {
    __shared__ __align__(16) char smem[131072];
    const int tid = threadIdx.x;
    const int l   = tid & 63;
    const int w   = tid >> 6;
    const int wr  = w >> 2, wc = w & 3;   // 2M x 4N waves, wave tile 128x64

    const int b   = blockIdx.x;
    const int q8  = nwg >> 3;
    const int g   = (b & 7) * q8 + (b >> 3);
    const int mi  = g & 15;
    const int ni  = g >> 4;
    const int m0  = mi * 256;
    const int n0  = ni * 256;

    // staging lane geometry (fp8: rows are NIN bytes in global, 128B in LDS)
    const int srow  = l >> 3;
    const int scolb = ((l & 7) ^ srow) * 16;          // byte offset (swizzle involution)
    const size_t slane = (size_t)srow * NIN + scolb;

    // frag-read geometry (32x32x64): row = l&31 (+offsets), read-key l&7
    const int arow = l & 31;
    const int swz  = l & 7;
    const int kgrp = (l >> 5) * 2;   // 16B-chunk offset within a 64B k-step

    f32x16 acc[4][2] = {};
    i32x8 aF[2][2], b0F[2], b1F[2];

    const unsigned char* xbase = xf8 + (size_t)m0 * NIN;
    const unsigned char* rbase = rf8 + (size_t)n0 * NIN;

    auto STAGE = [&](int buf, int kt, int q) {
        const int R = (q & 3) * 64 + w * 8;
        const unsigned char* src = ((q < 4) ? xbase : rbase)
                                   + (size_t)R * NIN + kt * 128 + slane;
        char* dst = smem + buf * 65536 + ((q >= 4) ? 32768 : 0) + R * 128;
        gload16(src, dst);
    };

    auto LDA = [&](int buf, int mh) {
        const char* base = smem + buf * 65536 + (wr * 128 + mh * 64 + arow) * 128;
        #pragma unroll
        for (int mb = 0; mb < 2; ++mb) {
            const char* rb = base + mb * 4096;        // 32 rows * 128B
            #pragma unroll
            for (int ks = 0; ks < 2; ++ks) {
                int c = ks * 4 + kgrp;
                i32x4 lo = *(const i32x4*)(rb + ((c ^ swz) * 16));
                i32x4 hi = *(const i32x4*)(rb + (((c + 1) ^ swz) * 16));
                aF[mb][ks] = __builtin_shufflevector(lo, hi, 0, 1, 2, 3, 4, 5, 6, 7);
            }
        }
    };
    auto LDB = [&](i32x8 (&bF)[2], int buf, int nh) {
        const char* base = smem + buf * 65536 + 32768 + (wc * 64 + nh * 32 + arow) * 128;
        #pragma unroll
        for (int ks = 0; ks < 2; ++ks) {
            int c = ks * 4 + kgrp;
            i32x4 lo = *(const i32x4*)(base + ((c ^ swz) * 16));
            i32x4 hi = *(const i32x4*)(base + (((c + 1) ^ swz) * 16));
            bF[ks] = __builtin_shufflevector(lo, hi, 0, 1, 2, 3, 4, 5, 6, 7);
        }
    };

    auto MM = [&](auto MHc, auto NHc, i32x8 (&bF)[2]) {
        constexpr int MH = decltype(MHc)::value;
        constexpr int NH = decltype(NHc)::value;
        __builtin_amdgcn_s_setprio(1);
        #pragma unroll
        for (int mb = 0; mb < 2; ++mb)
            #pragma unroll
            for (int ks = 0; ks < 2; ++ks)
                acc[MH * 2 + mb][NH] = __builtin_amdgcn_mfma_scale_f32_32x32x64_f8f6f4(
                    aF[mb][ks], bF[ks], acc[MH * 2 + mb][NH],
                    0, 0,        // fmt A = fp8 e4m3, fmt B = fp8 e4m3
                    0, 127,      // opsel_a, scale_a (e8m0 1.0)
                    0, 127);     // opsel_b, scale_b
        __builtin_amdgcn_s_setprio(0);
    };

    auto C0 = std::integral_constant<int, 0>{};
    auto C1 = std::integral_constant<int, 1>{};

    // r2's proven ledger: p0-p2 stage t1 q2..7; p3 stage t2 q0,1 + VMW2
    // (t1 landed); p4-p6 stage t2 q2..7; p7 stage t3 q0,1 + VMW2 (t2 landed).
    auto ITER = [&](auto LASTc, int t1, int t2, int t3) {
        constexpr bool LAST = decltype(LASTc)::value;
        LDA(0, 0); LDB(b0F, 0, 0);
        STAGE(1, t1, 2); STAGE(1, t1, 3);
        BAR; LGK0; MM(C0, C0, b0F); BAR;
        LDB(b1F, 0, 1);
        STAGE(1, t1, 4); STAGE(1, t1, 5);
        BAR; LGK0; MM(C0, C1, b1F); BAR;
        LDA(0, 1);
        STAGE(1, t1, 6); STAGE(1, t1, 7);
        BAR; LGK0; MM(C1, C1, b1F); BAR;
        if constexpr (!LAST) { STAGE(0, t2, 0); STAGE(0, t2, 1); }
        BAR; MM(C1, C0, b0F);
        if constexpr (LAST) { VMW0; } else { VMW2; }
        BAR;
        LDA(1, 0); LDB(b0F, 1, 0);
        if constexpr (!LAST) { STAGE(0, t2, 2); STAGE(0, t2, 3); }
        BAR; LGK0; MM(C0, C0, b0F); BAR;
        LDB(b1F, 1, 1);
        if constexpr (!LAST) { STAGE(0, t2, 4); STAGE(0, t2, 5); }
        BAR; LGK0; MM(C0, C1, b1F); BAR;
        LDA(1, 1);
        if constexpr (!LAST) { STAGE(0, t2, 6); STAGE(0, t2, 7); }
        BAR; LGK0; MM(C1, C1, b1F); BAR;
        if constexpr (!LAST) {
            STAGE(1, t3, 0); STAGE(1, t3, 1);
            BAR; MM(C1, C0, b0F); VMW2; BAR;
        } else {
            MM(C1, C0, b0F);
        }
    };

    // prologue: tile0 -> buf0 (q0..7), tile1 q0,1 -> buf1; vmcnt(2) -> t0 landed
    #pragma unroll
    for (int q = 0; q < 8; ++q) STAGE(0, 0, q);
    STAGE(1, 1, 0); STAGE(1, 1, 1);
    VMW2; BAR;

    // 8 K-tiles of 128 bytes -> 4 ITERs
    #pragma unroll 1
    for (int i = 0; i < 3; ++i)
        ITER(std::false_type{}, 2 * i + 1, 2 * i + 2, 2 * i + 3);
    ITER(std::true_type{}, 7, 8, 9);

    // epilogue (verified r7): out = acc + y0 + bias. 32x32 C/D:
    // col = l&31, row = (reg&3) + 8*(reg>>2) + 4*(l>>5)
    const int s    = s0 + (n0 >> 10);
    const int ocl0 = (n0 & 1023) + wc * 64 + (l & 31);
    float bv[2];
    #pragma unroll
    for (int nb = 0; nb < 2; ++nb) bv[nb] = bias[s * NOUT + ocl0 + nb * 32];
    float* outp = out + (size_t)s * NB * NOUT;
    const int rbase0 = m0 + wr * 128 + 4 * (l >> 5);
    #pragma unroll
    for (int mb = 0; mb < 4; ++mb) {
        #pragma unroll
        for (int nb = 0; nb < 2; ++nb) {
            const int colg = ocl0 + nb * 32;
            #pragma unroll
            for (int r = 0; r < 16; ++r) {
                int row = rbase0 + mb * 32 + (r & 3) + 8 * (r >> 2);
                size_t off = (size_t)row * NOUT + colg;   // index within one S-slice
                outp[off] = acc[mb][nb][r] + y0[off] + bv[nb];
            }
        }
    }
}

// ---- zero-scratch correctness fallback (only if ws_size is tiny) ----
__global__ void fused_fallback(const float* __restrict__ x, const float* __restrict__ wmu,
                               const float* __restrict__ wls, const float* __restrict__ r1,
                               const float* __restrict__ bmu, const float* __restrict__ bls,
                               const float* __restrict__ r2, float* __restrict__ out) {
    __shared__ float Xs[16][64];
    __shared__ float Ws[16][64];
    int b0 = blockIdx.x * 16, o0 = blockIdx.y * 16, s = blockIdx.z;
    int tb = threadIdx.x >> 4, to = threadIdx.x & 15;
    float acc = 0.f;
    for (int k0 = 0; k0 < NIN; k0 += 64) {
        __syncthreads();
        #pragma unroll
        for (int j = 0; j < 4; ++j) {
            int e = j * 256 + threadIdx.x;
            int r = e >> 6, cc = e & 63;
            Xs[r][cc] = x[(size_t)(b0 + r) * NIN + k0 + cc];
            size_t wi = (size_t)(o0 + r) * NIN + k0 + cc;
            Ws[r][cc] = wmu[wi] + __expf(wls[wi]) * r1[(size_t)s * NIN * NOUT + wi];
        }
        __syncthreads();
        for (int k = 0; k < 64; ++k) acc += Xs[tb][k] * Ws[to][k];
    }
    int o = o0 + to;
    out[((size_t)s * NB + b0 + tb) * NOUT + o] = acc + bmu[o] + __expf(bls[o]) * r2[s * NOUT + o];
}

extern "C" void kernel_launch(void* const* d_in, const int* in_sizes, int n_in,
                              void* d_out, int out_size, void* d_ws, size_t ws_size,
                              hipStream_t stream) {
    const float* x   = (const float*)d_in[0];
    const float* wmu = (const float*)d_in[1];
    const float* wls = (const float*)d_in[2];
    const float* bmu = (const float*)d_in[3];
    const float* bls = (const float*)d_in[4];
    const float* r1  = (const float*)d_in[5];
    const float* r2  = (const float*)d_in[6];
    const int S = in_sizes[6] / NOUT;
    float* out = (float*)d_out;

    const size_t xb_b   = (size_t)NB * NIN * 2;       // 8 MB  bf16 x
    const size_t xf8_b  = (size_t)NB * NIN;           // 4 MB  fp8 x
    const size_t wmub_b = (size_t)NOUT * NIN * 2;     // 2 MB  bf16 w_mu
    const size_t y0_b   = (size_t)NB * NOUT * 4;      // 16 MB f32 y0
    const size_t bias_b = (size_t)S * NOUT * 4;
    const size_t per_s  = (size_t)NOUT * NIN;         // 1 MB fp8 per sample
    const size_t base_b = xb_b + xf8_b + wmub_b + y0_b + bias_b;

    if (ws_size < base_b + per_s) {
        dim3 gg(NB / 16, NOUT / 16, S);
        fused_fallback<<<gg, 256, 0, stream>>>(x, wmu, wls, r1, bmu, bls, r2, out);
        return;
    }

    char* ws = (char*)d_ws;
    unsigned short* xb   = (unsigned short*)ws;
    unsigned char*  xf8  = (unsigned char*)(ws + xb_b);
    unsigned short* wmub = (unsigned short*)(ws + xb_b + xf8_b);
    float*          y0   = (float*)(ws + xb_b + xf8_b + wmub_b);
    float*          bias = (float*)(ws + xb_b + xf8_b + wmub_b + y0_b);
    unsigned char*  rf8  = (unsigned char*)(ws + base_b);

    int SC = (int)((ws_size - base_b) / per_s);
    if (SC > S) SC = S;

    cvt_x_kernel<<<NB * NIN / 1024, 256, 0, stream>>>(x, xb);
    cvt_x_kernel<<<NOUT * NIN / 1024, 256, 0, stream>>>(wmu, wmub);
    cvt_x_fp8<<<NB * NIN / 1024, 256, 0, stream>>>(x, (unsigned int*)xf8);
    bias_kernel<<<(S * NOUT + 255) / 256, 256, 0, stream>>>(bmu, bls, r2, bias, S * NOUT);

    // y0 = x . w_mu^T   (bf16, 64 blocks)
    gemm256<<<64, 512, 0, stream>>>(xb, wmub, y0, 64);

    for (int s0 = 0; s0 < S; s0 += SC) {
        int sc = (S - s0 < SC) ? (S - s0) : SC;
        cvt_r1_fp8<<<sc * (NOUT * NIN / 1024), 256, 0, stream>>>(wls, r1, (unsigned int*)rf8, s0);
        int nwg = 64 * sc;
        gemm256mx<<<nwg, 512, 0, stream>>>(xf8, rf8, y0, bias, out, s0, nwg);
    }
}

// Round 9
// 643.801 us; speedup vs baseline: 1.5331x; 1.1936x over previous
//
#include <hip/hip_runtime.h>
#include <hip/hip_bf16.h>
#include <hip/hip_fp8.h>
#include <stdint.h>
#include <type_traits>

#define NIN  1024
#define NOUT 1024
#define NB   4096   // batch

typedef float f32x4  __attribute__((ext_vector_type(4)));
typedef float f32x16 __attribute__((ext_vector_type(16)));
typedef __bf16 bf16x8 __attribute__((ext_vector_type(8)));
typedef int   i32x4 __attribute__((ext_vector_type(4)));
typedef int   i32x8 __attribute__((ext_vector_type(8)));

typedef const __attribute__((address_space(1))) unsigned int* gp1_t;
typedef __attribute__((address_space(3))) unsigned int* lp3_t;

__device__ __forceinline__ void gload16(const void* g, void* l) {
    __builtin_amdgcn_global_load_lds((gp1_t)g, (lp3_t)l, 16, 0, 0);
}

__device__ __forceinline__ unsigned short f2bf(float f) {
    __bf16 h = (__bf16)f;
    return __builtin_bit_cast(unsigned short, h);
}

// pack 4 floats -> 4 e4m3fn bytes
__device__ __forceinline__ unsigned int pk4_fp8(float a, float b, float c, float d) {
#if __has_builtin(__builtin_amdgcn_cvt_pk_fp8_f32)
    int p = __builtin_amdgcn_cvt_pk_fp8_f32(a, b, 0, false);
    p = __builtin_amdgcn_cvt_pk_fp8_f32(c, d, p, true);
    return (unsigned int)p;
#else
    __hip_fp8_e4m3 qa(a), qb(b), qc(c), qd(d);
    return (unsigned int)qa.__x | ((unsigned int)qb.__x << 8) |
           ((unsigned int)qc.__x << 16) | ((unsigned int)qd.__x << 24);
#endif
}

#define BAR   __builtin_amdgcn_s_barrier()
#define LGK0  do { asm volatile("s_waitcnt lgkmcnt(0)" ::: "memory"); __builtin_amdgcn_sched_barrier(0); } while (0)
#define VMW2  do { asm volatile("s_waitcnt vmcnt(2)"  ::: "memory"); __builtin_amdgcn_sched_barrier(0); } while (0)
#define VMW0  do { asm volatile("s_waitcnt vmcnt(0)"  ::: "memory"); __builtin_amdgcn_sched_barrier(0); } while (0)

// ---- prep: f32 -> bf16 ----
__global__ void cvt_x_kernel(const float* __restrict__ x, unsigned short* __restrict__ xb) {
    int i = blockIdx.x * blockDim.x + threadIdx.x;
    f32x4 v = reinterpret_cast<const f32x4*>(x)[i];
    ushort4 o;
    o.x = f2bf(v.x); o.y = f2bf(v.y); o.z = f2bf(v.z); o.w = f2bf(v.w);
    reinterpret_cast<ushort4*>(xb)[i] = o;
}

// ---- prep: x -> fp8 e4m3 ----
__global__ void cvt_x_fp8(const float* __restrict__ x, unsigned int* __restrict__ xf8) {
    int i = blockIdx.x * blockDim.x + threadIdx.x;
    f32x4 v = reinterpret_cast<const f32x4*>(x)[i];
    xf8[i] = pk4_fp8(v.x, v.y, v.z, v.w);
}

// ---- prep: rf8[c,o,i] = fp8( exp(wls[o,i]) * r1[s0+c,o,i] ) ----
// r1 is streamed once (268 MB): non-temporal load keeps it out of L2/L3.
__global__ void cvt_r1_fp8(const float* __restrict__ wls, const float* __restrict__ r1,
                           unsigned int* __restrict__ rf8, int s0) {
    int idx = blockIdx.x * blockDim.x + threadIdx.x;
    int i4 = idx & 262143;
    int c  = idx >> 18;
    f32x4 ls = reinterpret_cast<const f32x4*>(wls)[i4];
    const f32x4* rp = reinterpret_cast<const f32x4*>(r1 + ((size_t)(s0 + c) << 20));
    f32x4 r = __builtin_nontemporal_load(rp + i4);
    rf8[idx] = pk4_fp8(__expf(ls.x) * r.x, __expf(ls.y) * r.y,
                       __expf(ls.z) * r.z, __expf(ls.w) * r.w);
}

// ---- prep: bias[s,o] = b_mu[o] + exp(b_ls[o]) * r2[s,o] ----
__global__ void bias_kernel(const float* __restrict__ bmu, const float* __restrict__ bls,
                            const float* __restrict__ r2, float* __restrict__ bias, int total) {
    int i = blockIdx.x * blockDim.x + threadIdx.x;
    if (i < total) {
        int o = i & (NOUT - 1);
        bias[i] = bmu[o] + __expf(bls[o]) * r2[i];
    }
}

// =====================================================================
// bf16 256x256 8-phase GEMM (r2-proven schedule), used for y0 = x.w_mu^T
// =====================================================================
__launch_bounds__(512, 2)
__global__ void gemm256(const unsigned short* __restrict__ xb,
                        const unsigned short* __restrict__ wb,
                        float* __restrict__ out, int nwg) {
    __shared__ __align__(16) char smem[131072];
    const int tid = threadIdx.x;
    const int l   = tid & 63;
    const int w   = tid >> 6;
    const int wr  = w >> 2, wc = w & 3;

    const int b   = blockIdx.x;
    const int q8  = nwg >> 3;
    const int g   = (b & 7) * q8 + (b >> 3);
    const int mi  = g & 15;
    const int ni  = g >> 4;
    const int m0  = mi * 256;
    const int n0  = ni * 256;

    const int srow = l >> 3;
    const int scol = ((l & 7) ^ srow) * 8;
    const size_t slane = (size_t)srow * NIN + scol;

    const int rowp  = (l & 15) * 128;
    const int colp0 = ((l >> 4) ^ (l & 7)) << 4;

    f32x4 acc[8][4] = {};
    bf16x8 aF[4][2], b0F[2][2], b1F[2][2];

    const unsigned short* xbase = xb + (size_t)m0 * NIN;
    const unsigned short* wbase = wb + (size_t)n0 * NIN;

    auto STAGE = [&](int buf, int kt, int q) {
        const int R = (q & 3) * 64 + w * 8;
        const unsigned short* src = ((q < 4) ? xbase : wbase)
                                    + (size_t)R * NIN + kt * 64 + slane;
        char* dst = smem + buf * 65536 + ((q >= 4) ? 32768 : 0) + R * 128;
        gload16(src, dst);
    };
    auto LDA = [&](int buf, int mh) {
        const char* base = smem + buf * 65536 + (wr * 128 + mh * 64) * 128 + rowp;
        #pragma unroll
        for (int mb = 0; mb < 4; ++mb) {
            aF[mb][0] = *(const bf16x8*)(base + mb * 2048 + colp0);
            aF[mb][1] = *(const bf16x8*)(base + mb * 2048 + (colp0 ^ 64));
        }
    };
    auto LDB = [&](bf16x8 (&bF)[2][2], int buf, int nh) {
        const char* base = smem + buf * 65536 + 32768 + (wc * 64 + nh * 32) * 128 + rowp;
        #pragma unroll
        for (int nb = 0; nb < 2; ++nb) {
            bF[nb][0] = *(const bf16x8*)(base + nb * 2048 + colp0);
            bF[nb][1] = *(const bf16x8*)(base + nb * 2048 + (colp0 ^ 64));
        }
    };
    auto MM = [&](auto MHc, auto NHc, bf16x8 (&bF)[2][2]) {
        constexpr int MH = decltype(MHc)::value;
        constexpr int NH = decltype(NHc)::value;
        __builtin_amdgcn_s_setprio(1);
        #pragma unroll
        for (int mb = 0; mb < 4; ++mb)
            #pragma unroll
            for (int nb = 0; nb < 2; ++nb)
                #pragma unroll
                for (int kk = 0; kk < 2; ++kk)
                    acc[MH * 4 + mb][NH * 2 + nb] = __builtin_amdgcn_mfma_f32_16x16x32_bf16(
                        aF[mb][kk], bF[nb][kk], acc[MH * 4 + mb][NH * 2 + nb], 0, 0, 0);
        __builtin_amdgcn_s_setprio(0);
    };

    auto C0 = std::integral_constant<int, 0>{};
    auto C1 = std::integral_constant<int, 1>{};

    auto ITER = [&](auto LASTc, int t1, int t2, int t3) {
        constexpr bool LAST = decltype(LASTc)::value;
        LDA(0, 0); LDB(b0F, 0, 0);
        STAGE(1, t1, 2); STAGE(1, t1, 3);
        BAR; LGK0; MM(C0, C0, b0F); BAR;
        LDB(b1F, 0, 1);
        STAGE(1, t1, 4); STAGE(1, t1, 5);
        BAR; LGK0; MM(C0, C1, b1F); BAR;
        LDA(0, 1);
        STAGE(1, t1, 6); STAGE(1, t1, 7);
        BAR; LGK0; MM(C1, C1, b1F); BAR;
        if constexpr (!LAST) { STAGE(0, t2, 0); STAGE(0, t2, 1); }
        BAR; MM(C1, C0, b0F);
        if constexpr (LAST) { VMW0; } else { VMW2; }
        BAR;
        LDA(1, 0); LDB(b0F, 1, 0);
        if constexpr (!LAST) { STAGE(0, t2, 2); STAGE(0, t2, 3); }
        BAR; LGK0; MM(C0, C0, b0F); BAR;
        LDB(b1F, 1, 1);
        if constexpr (!LAST) { STAGE(0, t2, 4); STAGE(0, t2, 5); }
        BAR; LGK0; MM(C0, C1, b1F); BAR;
        LDA(1, 1);
        if constexpr (!LAST) { STAGE(0, t2, 6); STAGE(0, t2, 7); }
        BAR; LGK0; MM(C1, C1, b1F); BAR;
        if constexpr (!LAST) {
            STAGE(1, t3, 0); STAGE(1, t3, 1);
            BAR; MM(C1, C0, b0F); VMW2; BAR;
        } else {
            MM(C1, C0, b0F);
        }
    };

    #pragma unroll
    for (int q = 0; q < 8; ++q) STAGE(0, 0, q);
    STAGE(1, 1, 0); STAGE(1, 1, 1);
    VMW2; BAR;

    #pragma unroll 1
    for (int i = 0; i < 7; ++i)
        ITER(std::false_type{}, 2 * i + 1, 2 * i + 2, 2 * i + 3);
    ITER(std::true_type{}, 15, 16, 17);

    const int oc = n0 + wc * 64 + (l & 15);
    float* outp = out;
    #pragma unroll
    for (int mb = 0; mb < 8; ++mb) {
        #pragma unroll
        for (int i2 = 0; i2 < 4; ++i2) {
            int row = m0 + wr * 128 + mb * 16 + (l >> 4) * 4 + i2;
            float* rp = outp + (size_t)row * NOUT + oc;
            #pragma unroll
            for (int nb = 0; nb < 4; ++nb)
                rp[nb * 16] = acc[mb][nb][i2];
        }
    }
}

// =====================================================================
// MX-fp8 256x256 GEMM v4 = v3 K-loop + cache-preserving epilogue:
// stage each 64x256 output chunk in LDS (scalar ds_write, bank=col ->
// 2-way free), read back e4-linear (one 1024B row per wave-instr),
// add y0+bias via coalesced float4 loads, NON-TEMPORAL float4 stores
// so the 1.07-GB out stream bypasses L2/L3 and y0/rf8/xf8 stay cached.
// =====================================================================
__launch_bounds__(512, 2)
__global__ void gemm256mx(const unsigned char* __restrict__ xf8,
                          const unsigned char* __restrict__ rf8,
                          const float* __restrict__ y0,
                          const float* __restrict__ bias,
                          float* __restrict__ out, int s0, int nwg) {
    __shared__ __align__(16) char smem[131072];
    const int tid = threadIdx.x;
    const int l   = tid & 63;
    const int w   = tid >> 6;
    const int wr  = w >> 2, wc = w & 3;   // 2M x 4N waves, wave tile 128x64

    const int b   = blockIdx.x;
    const int q8  = nwg >> 3;
    const int g   = (b & 7) * q8 + (b >> 3);
    const int mi  = g & 15;
    const int ni  = g >> 4;
    const int m0  = mi * 256;
    const int n0  = ni * 256;

    // staging lane geometry (fp8: rows are NIN bytes in global, 128B in LDS)
    const int srow  = l >> 3;
    const int scolb = ((l & 7) ^ srow) * 16;          // byte offset (swizzle involution)
    const size_t slane = (size_t)srow * NIN + scolb;

    // frag-read geometry (32x32x64): row = l&31 (+offsets), read-key l&7
    const int arow = l & 31;
    const int swz  = l & 7;
    const int kgrp = (l >> 5) * 2;   // 16B-chunk offset within a 64B k-step

    f32x16 acc[4][2] = {};
    i32x8 aF[2][2], b0F[2], b1F[2];

    const unsigned char* xbase = xf8 + (size_t)m0 * NIN;
    const unsigned char* rbase = rf8 + (size_t)n0 * NIN;

    auto STAGE = [&](int buf, int kt, int q) {
        const int R = (q & 3) * 64 + w * 8;
        const unsigned char* src = ((q < 4) ? xbase : rbase)
                                   + (size_t)R * NIN + kt * 128 + slane;
        char* dst = smem + buf * 65536 + ((q >= 4) ? 32768 : 0) + R * 128;
        gload16(src, dst);
    };

    auto LDA = [&](int buf, int mh) {
        const char* base = smem + buf * 65536 + (wr * 128 + mh * 64 + arow) * 128;
        #pragma unroll
        for (int mb = 0; mb < 2; ++mb) {
            const char* rb = base + mb * 4096;        // 32 rows * 128B
            #pragma unroll
            for (int ks = 0; ks < 2; ++ks) {
                int c = ks * 4 + kgrp;
                i32x4 lo = *(const i32x4*)(rb + ((c ^ swz) * 16));
                i32x4 hi = *(const i32x4*)(rb + (((c + 1) ^ swz) * 16));
                aF[mb][ks] = __builtin_shufflevector(lo, hi, 0, 1, 2, 3, 4, 5, 6, 7);
            }
        }
    };
    auto LDB = [&](i32x8 (&bF)[2], int buf, int nh) {
        const char* base = smem + buf * 65536 + 32768 + (wc * 64 + nh * 32 + arow) * 128;
        #pragma unroll
        for (int ks = 0; ks < 2; ++ks) {
            int c = ks * 4 + kgrp;
            i32x4 lo = *(const i32x4*)(base + ((c ^ swz) * 16));
            i32x4 hi = *(const i32x4*)(base + (((c + 1) ^ swz) * 16));
            bF[ks] = __builtin_shufflevector(lo, hi, 0, 1, 2, 3, 4, 5, 6, 7);
        }
    };

    auto MM = [&](auto MHc, auto NHc, i32x8 (&bF)[2]) {
        constexpr int MH = decltype(MHc)::value;
        constexpr int NH = decltype(NHc)::value;
        __builtin_amdgcn_s_setprio(1);
        #pragma unroll
        for (int mb = 0; mb < 2; ++mb)
            #pragma unroll
            for (int ks = 0; ks < 2; ++ks)
                acc[MH * 2 + mb][NH] = __builtin_amdgcn_mfma_scale_f32_32x32x64_f8f6f4(
                    aF[mb][ks], bF[ks], acc[MH * 2 + mb][NH],
                    0, 0,        // fmt A = fp8 e4m3, fmt B = fp8 e4m3
                    0, 127,      // opsel_a, scale_a (e8m0 1.0)
                    0, 127);     // opsel_b, scale_b
        __builtin_amdgcn_s_setprio(0);
    };

    auto C0 = std::integral_constant<int, 0>{};
    auto C1 = std::integral_constant<int, 1>{};

    auto ITER = [&](auto LASTc, int t1, int t2, int t3) {
        constexpr bool LAST = decltype(LASTc)::value;
        LDA(0, 0); LDB(b0F, 0, 0);
        STAGE(1, t1, 2); STAGE(1, t1, 3);
        BAR; LGK0; MM(C0, C0, b0F); BAR;
        LDB(b1F, 0, 1);
        STAGE(1, t1, 4); STAGE(1, t1, 5);
        BAR; LGK0; MM(C0, C1, b1F); BAR;
        LDA(0, 1);
        STAGE(1, t1, 6); STAGE(1, t1, 7);
        BAR; LGK0; MM(C1, C1, b1F); BAR;
        if constexpr (!LAST) { STAGE(0, t2, 0); STAGE(0, t2, 1); }
        BAR; MM(C1, C0, b0F);
        if constexpr (LAST) { VMW0; } else { VMW2; }
        BAR;
        LDA(1, 0); LDB(b0F, 1, 0);
        if constexpr (!LAST) { STAGE(0, t2, 2); STAGE(0, t2, 3); }
        BAR; LGK0; MM(C0, C0, b0F); BAR;
        LDB(b1F, 1, 1);
        if constexpr (!LAST) { STAGE(0, t2, 4); STAGE(0, t2, 5); }
        BAR; LGK0; MM(C0, C1, b1F); BAR;
        LDA(1, 1);
        if constexpr (!LAST) { STAGE(0, t2, 6); STAGE(0, t2, 7); }
        BAR; LGK0; MM(C1, C1, b1F); BAR;
        if constexpr (!LAST) {
            STAGE(1, t3, 0); STAGE(1, t3, 1);
            BAR; MM(C1, C0, b0F); VMW2; BAR;
        } else {
            MM(C1, C0, b0F);
        }
    };

    // prologue: tile0 -> buf0 (q0..7), tile1 q0,1 -> buf1; vmcnt(2) -> t0 landed
    #pragma unroll
    for (int q = 0; q < 8; ++q) STAGE(0, 0, q);
    STAGE(1, 1, 0); STAGE(1, 1, 1);
    VMW2; BAR;

    // 8 K-tiles of 128 bytes -> 4 ITERs
    #pragma unroll 1
    for (int i = 0; i < 3; ++i)
        ITER(std::false_type{}, 2 * i + 1, 2 * i + 2, 2 * i + 3);
    ITER(std::true_type{}, 7, 8, 9);

    // ---- epilogue v2: LDS transpose + y0 + bias + NT float4 stores ----
    // C/D map (verified r7): col = l&31, row = (reg&3) + 8*(reg>>2) + 4*(l>>5)
    const int s   = s0 + (n0 >> 10);
    const int n0c = n0 & 1023;
    float* outp = out + (size_t)s * NB * NOUT;
    float* lds_f = (float*)smem;     // [64][256] f32 chunk staging (64 KB)
    const f32x4 bvv = *(const f32x4*)(bias + (size_t)s * NOUT + n0c + l * 4);

    #pragma unroll
    for (int c = 0; c < 4; ++c) {    // chunk = rows [c*64, c*64+64) of the tile
        if (wr == (c >> 1)) {        // waves owning these rows write them
            #pragma unroll
            for (int mbh = 0; mbh < 2; ++mbh) {
                const int mb = (c & 1) * 2 + mbh;   // compile-time (c unrolled)
                #pragma unroll
                for (int nb = 0; nb < 2; ++nb) {
                    const int col = wc * 64 + nb * 32 + (l & 31);
                    #pragma unroll
                    for (int r = 0; r < 16; ++r) {
                        int rl = mbh * 32 + 4 * (l >> 5) + (r & 3) + 8 * (r >> 2);
                        lds_f[rl * 256 + col] = acc[mb][nb][r];
                    }
                }
            }
        }
        LGK0; BAR;                   // chunk writes visible to all waves
        #pragma unroll
        for (int k = 0; k < 8; ++k) {
            const int rl  = k * 8 + w;               // local row in chunk
            const int row = m0 + c * 64 + rl;        // global m-row
            f32x4 v  = *(const f32x4*)(lds_f + (rl * 64 + l) * 4);
            f32x4 yv = *(const f32x4*)(y0 + (size_t)row * NOUT + n0c + l * 4);
            f32x4 o  = v + yv + bvv;
            __builtin_nontemporal_store(o, (f32x4*)(outp + (size_t)row * NOUT + n0c + l * 4));
        }
        BAR;                         // reads done before next chunk overwrite
    }
}

// ---- zero-scratch correctness fallback (only if ws_size is tiny) ----
__global__ void fused_fallback(const float* __restrict__ x, const float* __restrict__ wmu,
                               const float* __restrict__ wls, const float* __restrict__ r1,
                               const float* __restrict__ bmu, const float* __restrict__ bls,
                               const float* __restrict__ r2, float* __restrict__ out) {
    __shared__ float Xs[16][64];
    __shared__ float Ws[16][64];
    int b0 = blockIdx.x * 16, o0 = blockIdx.y * 16, s = blockIdx.z;
    int tb = threadIdx.x >> 4, to = threadIdx.x & 15;
    float acc = 0.f;
    for (int k0 = 0; k0 < NIN; k0 += 64) {
        __syncthreads();
        #pragma unroll
        for (int j = 0; j < 4; ++j) {
            int e = j * 256 + threadIdx.x;
            int r = e >> 6, cc = e & 63;
            Xs[r][cc] = x[(size_t)(b0 + r) * NIN + k0 + cc];
            size_t wi = (size_t)(o0 + r) * NIN + k0 + cc;
            Ws[r][cc] = wmu[wi] + __expf(wls[wi]) * r1[(size_t)s * NIN * NOUT + wi];
        }
        __syncthreads();
        for (int k = 0; k < 64; ++k) acc += Xs[tb][k] * Ws[to][k];
    }
    int o = o0 + to;
    out[((size_t)s * NB + b0 + tb) * NOUT + o] = acc + bmu[o] + __expf(bls[o]) * r2[s * NOUT + o];
}

extern "C" void kernel_launch(void* const* d_in, const int* in_sizes, int n_in,
                              void* d_out, int out_size, void* d_ws, size_t ws_size,
                              hipStream_t stream) {
    const float* x   = (const float*)d_in[0];
    const float* wmu = (const float*)d_in[1];
    const float* wls = (const float*)d_in[2];
    const float* bmu = (const float*)d_in[3];
    const float* bls = (const float*)d_in[4];
    const float* r1  = (const float*)d_in[5];
    const float* r2  = (const float*)d_in[6];
    const int S = in_sizes[6] / NOUT;
    float* out = (float*)d_out;

    const size_t xb_b   = (size_t)NB * NIN * 2;       // 8 MB  bf16 x
    const size_t xf8_b  = (size_t)NB * NIN;           // 4 MB  fp8 x
    const size_t wmub_b = (size_t)NOUT * NIN * 2;     // 2 MB  bf16 w_mu
    const size_t y0_b   = (size_t)NB * NOUT * 4;      // 16 MB f32 y0
    const size_t bias_b = (size_t)S * NOUT * 4;
    const size_t per_s  = (size_t)NOUT * NIN;         // 1 MB fp8 per sample
    const size_t base_b = xb_b + xf8_b + wmub_b + y0_b + bias_b;

    if (ws_size < base_b + per_s) {
        dim3 gg(NB / 16, NOUT / 16, S);
        fused_fallback<<<gg, 256, 0, stream>>>(x, wmu, wls, r1, bmu, bls, r2, out);
        return;
    }

    char* ws = (char*)d_ws;
    unsigned short* xb   = (unsigned short*)ws;
    unsigned char*  xf8  = (unsigned char*)(ws + xb_b);
    unsigned short* wmub = (unsigned short*)(ws + xb_b + xf8_b);
    float*          y0   = (float*)(ws + xb_b + xf8_b + wmub_b);
    float*          bias = (float*)(ws + xb_b + xf8_b + wmub_b + y0_b);
    unsigned char*  rf8  = (unsigned char*)(ws + base_b);

    int SC = (int)((ws_size - base_b) / per_s);
    if (SC > S) SC = S;

    cvt_x_kernel<<<NB * NIN / 1024, 256, 0, stream>>>(x, xb);
    cvt_x_kernel<<<NOUT * NIN / 1024, 256, 0, stream>>>(wmu, wmub);
    cvt_x_fp8<<<NB * NIN / 1024, 256, 0, stream>>>(x, (unsigned int*)xf8);
    bias_kernel<<<(S * NOUT + 255) / 256, 256, 0, stream>>>(bmu, bls, r2, bias, S * NOUT);

    // y0 = x . w_mu^T   (bf16, 64 blocks)
    gemm256<<<64, 512, 0, stream>>>(xb, wmub, y0, 64);

    for (int s0 = 0; s0 < S; s0 += SC) {
        int sc = (S - s0 < SC) ? (S - s0) : SC;
        cvt_r1_fp8<<<sc * (NOUT * NIN / 1024), 256, 0, stream>>>(wls, r1, (unsigned int*)rf8, s0);
        int nwg = 64 * sc;
        gemm256mx<<<nwg, 512, 0, stream>>>(xf8, rf8, y0, bias, out, s0, nwg);
    }
}

// Round 10
// 561.475 us; speedup vs baseline: 1.7579x; 1.1466x over previous
//
#include <hip/hip_runtime.h>
#include <hip/hip_bf16.h>
#include <hip/hip_fp8.h>
#include <stdint.h>
#include <type_traits>

#define NIN  1024
#define NOUT 1024
#define NB   4096   // batch

typedef float f32x4  __attribute__((ext_vector_type(4)));
typedef float f32x16 __attribute__((ext_vector_type(16)));
typedef __bf16 bf16x8 __attribute__((ext_vector_type(8)));
typedef int   i32x4 __attribute__((ext_vector_type(4)));
typedef int   i32x8 __attribute__((ext_vector_type(8)));

typedef const __attribute__((address_space(1))) unsigned int* gp1_t;
typedef __attribute__((address_space(3))) unsigned int* lp3_t;

__device__ __forceinline__ void gload16(const void* g, void* l) {
    __builtin_amdgcn_global_load_lds((gp1_t)g, (lp3_t)l, 16, 0, 0);
}

__device__ __forceinline__ unsigned short f2bf(float f) {
    __bf16 h = (__bf16)f;
    return __builtin_bit_cast(unsigned short, h);
}

// pack 4 floats -> 4 e4m3fn bytes
__device__ __forceinline__ unsigned int pk4_fp8(float a, float b, float c, float d) {
#if __has_builtin(__builtin_amdgcn_cvt_pk_fp8_f32)
    int p = __builtin_amdgcn_cvt_pk_fp8_f32(a, b, 0, false);
    p = __builtin_amdgcn_cvt_pk_fp8_f32(c, d, p, true);
    return (unsigned int)p;
#else
    __hip_fp8_e4m3 qa(a), qb(b), qc(c), qd(d);
    return (unsigned int)qa.__x | ((unsigned int)qb.__x << 8) |
           ((unsigned int)qc.__x << 16) | ((unsigned int)qd.__x << 24);
#endif
}

#define BAR   __builtin_amdgcn_s_barrier()
#define LGK0  do { asm volatile("s_waitcnt lgkmcnt(0)" ::: "memory"); __builtin_amdgcn_sched_barrier(0); } while (0)
#define VMW8  do { asm volatile("s_waitcnt vmcnt(8)"  ::: "memory"); __builtin_amdgcn_sched_barrier(0); } while (0)
#define VMW2  do { asm volatile("s_waitcnt vmcnt(2)"  ::: "memory"); __builtin_amdgcn_sched_barrier(0); } while (0)
#define VMW0  do { asm volatile("s_waitcnt vmcnt(0)"  ::: "memory"); __builtin_amdgcn_sched_barrier(0); } while (0)

// ---- prep: f32 -> bf16 ----
__global__ void cvt_x_kernel(const float* __restrict__ x, unsigned short* __restrict__ xb) {
    int i = blockIdx.x * blockDim.x + threadIdx.x;
    f32x4 v = reinterpret_cast<const f32x4*>(x)[i];
    ushort4 o;
    o.x = f2bf(v.x); o.y = f2bf(v.y); o.z = f2bf(v.z); o.w = f2bf(v.w);
    reinterpret_cast<ushort4*>(xb)[i] = o;
}

// ---- prep: x -> fp8 e4m3 ----
__global__ void cvt_x_fp8(const float* __restrict__ x, unsigned int* __restrict__ xf8) {
    int i = blockIdx.x * blockDim.x + threadIdx.x;
    f32x4 v = reinterpret_cast<const f32x4*>(x)[i];
    xf8[i] = pk4_fp8(v.x, v.y, v.z, v.w);
}

// ---- prep: rf8[c,o,i] = fp8( exp(wls[o,i]) * r1[s0+c,o,i] ) ----
// r1 is streamed once (268 MB): non-temporal load keeps it out of L2/L3.
__global__ void cvt_r1_fp8(const float* __restrict__ wls, const float* __restrict__ r1,
                           unsigned int* __restrict__ rf8, int s0) {
    int idx = blockIdx.x * blockDim.x + threadIdx.x;
    int i4 = idx & 262143;
    int c  = idx >> 18;
    f32x4 ls = reinterpret_cast<const f32x4*>(wls)[i4];
    const f32x4* rp = reinterpret_cast<const f32x4*>(r1 + ((size_t)(s0 + c) << 20));
    f32x4 r = __builtin_nontemporal_load(rp + i4);
    rf8[idx] = pk4_fp8(__expf(ls.x) * r.x, __expf(ls.y) * r.y,
                       __expf(ls.z) * r.z, __expf(ls.w) * r.w);
}

// ---- prep: bias[s,o] = b_mu[o] + exp(b_ls[o]) * r2[s,o] ----
__global__ void bias_kernel(const float* __restrict__ bmu, const float* __restrict__ bls,
                            const float* __restrict__ r2, float* __restrict__ bias, int total) {
    int i = blockIdx.x * blockDim.x + threadIdx.x;
    if (i < total) {
        int o = i & (NOUT - 1);
        bias[i] = bmu[o] + __expf(bls[o]) * r2[i];
    }
}

// =====================================================================
// bf16 256x256 8-phase GEMM (r2-proven schedule), used for y0 = x.w_mu^T
// =====================================================================
__launch_bounds__(512, 2)
__global__ void gemm256(const unsigned short* __restrict__ xb,
                        const unsigned short* __restrict__ wb,
                        float* __restrict__ out, int nwg) {
    __shared__ __align__(16) char smem[131072];
    const int tid = threadIdx.x;
    const int l   = tid & 63;
    const int w   = tid >> 6;
    const int wr  = w >> 2, wc = w & 3;

    const int b   = blockIdx.x;
    const int q8  = nwg >> 3;
    const int g   = (b & 7) * q8 + (b >> 3);
    const int mi  = g & 15;
    const int ni  = g >> 4;
    const int m0  = mi * 256;
    const int n0  = ni * 256;

    const int srow = l >> 3;
    const int scol = ((l & 7) ^ srow) * 8;
    const size_t slane = (size_t)srow * NIN + scol;

    const int rowp  = (l & 15) * 128;
    const int colp0 = ((l >> 4) ^ (l & 7)) << 4;

    f32x4 acc[8][4] = {};
    bf16x8 aF[4][2], b0F[2][2], b1F[2][2];

    const unsigned short* xbase = xb + (size_t)m0 * NIN;
    const unsigned short* wbase = wb + (size_t)n0 * NIN;

    auto STAGE = [&](int buf, int kt, int q) {
        const int R = (q & 3) * 64 + w * 8;
        const unsigned short* src = ((q < 4) ? xbase : wbase)
                                    + (size_t)R * NIN + kt * 64 + slane;
        char* dst = smem + buf * 65536 + ((q >= 4) ? 32768 : 0) + R * 128;
        gload16(src, dst);
    };
    auto LDA = [&](int buf, int mh) {
        const char* base = smem + buf * 65536 + (wr * 128 + mh * 64) * 128 + rowp;
        #pragma unroll
        for (int mb = 0; mb < 4; ++mb) {
            aF[mb][0] = *(const bf16x8*)(base + mb * 2048 + colp0);
            aF[mb][1] = *(const bf16x8*)(base + mb * 2048 + (colp0 ^ 64));
        }
    };
    auto LDB = [&](bf16x8 (&bF)[2][2], int buf, int nh) {
        const char* base = smem + buf * 65536 + 32768 + (wc * 64 + nh * 32) * 128 + rowp;
        #pragma unroll
        for (int nb = 0; nb < 2; ++nb) {
            bF[nb][0] = *(const bf16x8*)(base + nb * 2048 + colp0);
            bF[nb][1] = *(const bf16x8*)(base + nb * 2048 + (colp0 ^ 64));
        }
    };
    auto MM = [&](auto MHc, auto NHc, bf16x8 (&bF)[2][2]) {
        constexpr int MH = decltype(MHc)::value;
        constexpr int NH = decltype(NHc)::value;
        __builtin_amdgcn_s_setprio(1);
        #pragma unroll
        for (int mb = 0; mb < 4; ++mb)
            #pragma unroll
            for (int nb = 0; nb < 2; ++nb)
                #pragma unroll
                for (int kk = 0; kk < 2; ++kk)
                    acc[MH * 4 + mb][NH * 2 + nb] = __builtin_amdgcn_mfma_f32_16x16x32_bf16(
                        aF[mb][kk], bF[nb][kk], acc[MH * 4 + mb][NH * 2 + nb], 0, 0, 0);
        __builtin_amdgcn_s_setprio(0);
    };

    auto C0 = std::integral_constant<int, 0>{};
    auto C1 = std::integral_constant<int, 1>{};

    auto ITER = [&](auto LASTc, int t1, int t2, int t3) {
        constexpr bool LAST = decltype(LASTc)::value;
        LDA(0, 0); LDB(b0F, 0, 0);
        STAGE(1, t1, 2); STAGE(1, t1, 3);
        BAR; LGK0; MM(C0, C0, b0F); BAR;
        LDB(b1F, 0, 1);
        STAGE(1, t1, 4); STAGE(1, t1, 5);
        BAR; LGK0; MM(C0, C1, b1F); BAR;
        LDA(0, 1);
        STAGE(1, t1, 6); STAGE(1, t1, 7);
        BAR; LGK0; MM(C1, C1, b1F); BAR;
        if constexpr (!LAST) { STAGE(0, t2, 0); STAGE(0, t2, 1); }
        BAR; MM(C1, C0, b0F);
        if constexpr (LAST) { VMW0; } else { VMW2; }
        BAR;
        LDA(1, 0); LDB(b0F, 1, 0);
        if constexpr (!LAST) { STAGE(0, t2, 2); STAGE(0, t2, 3); }
        BAR; LGK0; MM(C0, C0, b0F); BAR;
        LDB(b1F, 1, 1);
        if constexpr (!LAST) { STAGE(0, t2, 4); STAGE(0, t2, 5); }
        BAR; LGK0; MM(C0, C1, b1F); BAR;
        LDA(1, 1);
        if constexpr (!LAST) { STAGE(0, t2, 6); STAGE(0, t2, 7); }
        BAR; LGK0; MM(C1, C1, b1F); BAR;
        if constexpr (!LAST) {
            STAGE(1, t3, 0); STAGE(1, t3, 1);
            BAR; MM(C1, C0, b0F); VMW2; BAR;
        } else {
            MM(C1, C0, b0F);
        }
    };

    #pragma unroll
    for (int q = 0; q < 8; ++q) STAGE(0, 0, q);
    STAGE(1, 1, 0); STAGE(1, 1, 1);
    VMW2; BAR;

    #pragma unroll 1
    for (int i = 0; i < 7; ++i)
        ITER(std::false_type{}, 2 * i + 1, 2 * i + 2, 2 * i + 3);
    ITER(std::true_type{}, 15, 16, 17);

    const int oc = n0 + wc * 64 + (l & 15);
    float* outp = out;
    #pragma unroll
    for (int mb = 0; mb < 8; ++mb) {
        #pragma unroll
        for (int i2 = 0; i2 < 4; ++i2) {
            int row = m0 + wr * 128 + mb * 16 + (l >> 4) * 4 + i2;
            float* rp = outp + (size_t)row * NOUT + oc;
            #pragma unroll
            for (int nb = 0; nb < 4; ++nb)
                rp[nb * 16] = acc[mb][nb][i2];
        }
    }
}

// =====================================================================
// MX-fp8 256x256 GEMM v5 = v4 K-loop math + two memory-side fixes:
//  (a) ni-FASTEST grid order: consecutive blocks on an XCD keep the
//      SAME A-panel (256KB) + y0 slice (1MB) L2-resident and stream B
//      once each (B re-reads across mi hit L3 where rf8 is resident).
//  (b) burst deep-slack staging: all 8 units of a tile issued right
//      after the barrier that frees its buffer, gated by vmcnt(8)
//      4 phases (~2000 cyc) later. Ledger: gate sees old tile (<=8)
//      + new burst (8) outstanding -> vmcnt(8) proves old tile landed.
// =====================================================================
__launch_bounds__(512, 2)
__global__ void gemm256mx(const unsigned char* __restrict__ xf8,
                          const unsigned char* __restrict__ rf8,
                          const float* __restrict__ y0,
                          const float* __restrict__ bias,
                          float* __restrict__ out, int s0, int nwg) {
    __shared__ __align__(16) char smem[131072];
    const int tid = threadIdx.x;
    const int l   = tid & 63;
    const int w   = tid >> 6;
    const int wr  = w >> 2, wc = w & 3;   // 2M x 4N waves, wave tile 128x64

    const int b   = blockIdx.x;
    const int q8  = nwg >> 3;
    const int g   = (b & 7) * q8 + (b >> 3);
    const int nni = nwg >> 4;             // number of ni values (= 4*sc)
    const int mi  = g / nni;              // SLOW: A-panel + y0 slice stay in L2
    const int ni  = g - mi * nni;         // FAST: B streams, re-read via L3
    const int m0  = mi * 256;
    const int n0  = ni * 256;

    // staging lane geometry (fp8: rows are NIN bytes in global, 128B in LDS)
    const int srow  = l >> 3;
    const int scolb = ((l & 7) ^ srow) * 16;          // byte offset (swizzle involution)
    const size_t slane = (size_t)srow * NIN + scolb;

    // frag-read geometry (32x32x64): row = l&31 (+offsets), read-key l&7
    const int arow = l & 31;
    const int swz  = l & 7;
    const int kgrp = (l >> 5) * 2;   // 16B-chunk offset within a 64B k-step

    f32x16 acc[4][2] = {};
    i32x8 aF[2][2], b0F[2], b1F[2];

    const unsigned char* xbase = xf8 + (size_t)m0 * NIN;
    const unsigned char* rbase = rf8 + (size_t)n0 * NIN;

    auto STAGE = [&](int buf, int kt, int q) {
        const int R = (q & 3) * 64 + w * 8;
        const unsigned char* src = ((q < 4) ? xbase : rbase)
                                   + (size_t)R * NIN + kt * 128 + slane;
        char* dst = smem + buf * 65536 + ((q >= 4) ? 32768 : 0) + R * 128;
        gload16(src, dst);
    };
    auto STAGE8 = [&](int buf, int kt) {
        #pragma unroll
        for (int q = 0; q < 8; ++q) STAGE(buf, kt, q);
    };

    auto LDA = [&](int buf, int mh) {
        const char* base = smem + buf * 65536 + (wr * 128 + mh * 64 + arow) * 128;
        #pragma unroll
        for (int mb = 0; mb < 2; ++mb) {
            const char* rb = base + mb * 4096;        // 32 rows * 128B
            #pragma unroll
            for (int ks = 0; ks < 2; ++ks) {
                int c = ks * 4 + kgrp;
                i32x4 lo = *(const i32x4*)(rb + ((c ^ swz) * 16));
                i32x4 hi = *(const i32x4*)(rb + (((c + 1) ^ swz) * 16));
                aF[mb][ks] = __builtin_shufflevector(lo, hi, 0, 1, 2, 3, 4, 5, 6, 7);
            }
        }
    };
    auto LDB = [&](i32x8 (&bF)[2], int buf, int nh) {
        const char* base = smem + buf * 65536 + 32768 + (wc * 64 + nh * 32 + arow) * 128;
        #pragma unroll
        for (int ks = 0; ks < 2; ++ks) {
            int c = ks * 4 + kgrp;
            i32x4 lo = *(const i32x4*)(base + ((c ^ swz) * 16));
            i32x4 hi = *(const i32x4*)(base + (((c + 1) ^ swz) * 16));
            bF[ks] = __builtin_shufflevector(lo, hi, 0, 1, 2, 3, 4, 5, 6, 7);
        }
    };

    auto MM = [&](auto MHc, auto NHc, i32x8 (&bF)[2]) {
        constexpr int MH = decltype(MHc)::value;
        constexpr int NH = decltype(NHc)::value;
        __builtin_amdgcn_s_setprio(1);
        #pragma unroll
        for (int mb = 0; mb < 2; ++mb)
            #pragma unroll
            for (int ks = 0; ks < 2; ++ks)
                acc[MH * 2 + mb][NH] = __builtin_amdgcn_mfma_scale_f32_32x32x64_f8f6f4(
                    aF[mb][ks], bF[ks], acc[MH * 2 + mb][NH],
                    0, 0,        // fmt A = fp8 e4m3, fmt B = fp8 e4m3
                    0, 127,      // opsel_a, scale_a (e8m0 1.0)
                    0, 127);     // opsel_b, scale_b
        __builtin_amdgcn_s_setprio(0);
    };

    auto C0 = std::integral_constant<int, 0>{};
    auto C1 = std::integral_constant<int, 1>{};

    // ITER computes tiles t (buf0), t+1 (buf1); burst-stages t2=t+2 (p3,
    // after buf0's reads all complete) and t3=t+3 (p7). Gates: p3 vmcnt(8)
    // -> t+1 landed (staged 4 phases ago); p7 vmcnt(8) -> t+2 landed.
    auto ITER = [&](auto LASTc, int t2, int t3) {
        constexpr bool LAST = decltype(LASTc)::value;
        // p0-p2: buf0 frag reads + MFMA (no staging)
        LDA(0, 0); LDB(b0F, 0, 0);
        BAR; LGK0; MM(C0, C0, b0F); BAR;
        LDB(b1F, 0, 1);
        BAR; LGK0; MM(C0, C1, b1F); BAR;
        LDA(0, 1);
        BAR; LGK0; MM(C1, C1, b1F); BAR;   // after this BAR: all buf0 reads done
        // p3: burst t2 -> buf0 ; gate buf1 (t+1)
        if constexpr (!LAST) STAGE8(0, t2);
        BAR; MM(C1, C0, b0F);
        if constexpr (LAST) { VMW0; } else { VMW8; }
        BAR;
        // p4-p6: buf1 frag reads + MFMA
        LDA(1, 0); LDB(b0F, 1, 0);
        BAR; LGK0; MM(C0, C0, b0F); BAR;
        LDB(b1F, 1, 1);
        BAR; LGK0; MM(C0, C1, b1F); BAR;
        LDA(1, 1);
        BAR; LGK0; MM(C1, C1, b1F); BAR;   // all buf1 reads done
        // p7: burst t3 -> buf1 ; gate buf0 (t+2)
        if constexpr (!LAST) {
            STAGE8(1, t3);
            BAR; MM(C1, C0, b0F); VMW8; BAR;
        } else {
            MM(C1, C0, b0F);
        }
    };

    // prologue: tile0 -> buf0, tile1 -> buf1 (16 loads); vmcnt(8) -> t0 landed
    STAGE8(0, 0);
    STAGE8(1, 1);
    VMW8; BAR;

    // 8 K-tiles of 128 bytes -> 4 ITERs
    #pragma unroll 1
    for (int i = 0; i < 3; ++i)
        ITER(std::false_type{}, 2 * i + 2, 2 * i + 3);
    ITER(std::true_type{}, 8, 9);

    // ---- epilogue (r9-proven): LDS transpose + y0 + bias + NT f4 stores ----
    // C/D map (verified r7): col = l&31, row = (reg&3) + 8*(reg>>2) + 4*(l>>5)
    const int s   = s0 + (n0 >> 10);
    const int n0c = n0 & 1023;
    float* outp = out + (size_t)s * NB * NOUT;
    float* lds_f = (float*)smem;     // [64][256] f32 chunk staging (64 KB)
    const f32x4 bvv = *(const f32x4*)(bias + (size_t)s * NOUT + n0c + l * 4);

    #pragma unroll
    for (int c = 0; c < 4; ++c) {    // chunk = rows [c*64, c*64+64) of the tile
        if (wr == (c >> 1)) {        // waves owning these rows write them
            #pragma unroll
            for (int mbh = 0; mbh < 2; ++mbh) {
                const int mb = (c & 1) * 2 + mbh;   // compile-time (c unrolled)
                #pragma unroll
                for (int nb = 0; nb < 2; ++nb) {
                    const int col = wc * 64 + nb * 32 + (l & 31);
                    #pragma unroll
                    for (int r = 0; r < 16; ++r) {
                        int rl = mbh * 32 + 4 * (l >> 5) + (r & 3) + 8 * (r >> 2);
                        lds_f[rl * 256 + col] = acc[mb][nb][r];
                    }
                }
            }
        }
        LGK0; BAR;                   // chunk writes visible to all waves
        #pragma unroll
        for (int k = 0; k < 8; ++k) {
            const int rl  = k * 8 + w;               // local row in chunk
            const int row = m0 + c * 64 + rl;        // global m-row
            f32x4 v  = *(const f32x4*)(lds_f + (rl * 64 + l) * 4);
            f32x4 yv = *(const f32x4*)(y0 + (size_t)row * NOUT + n0c + l * 4);
            f32x4 o  = v + yv + bvv;
            __builtin_nontemporal_store(o, (f32x4*)(outp + (size_t)row * NOUT + n0c + l * 4));
        }
        BAR;                         // reads done before next chunk overwrite
    }
}

// ---- zero-scratch correctness fallback (only if ws_size is tiny) ----
__global__ void fused_fallback(const float* __restrict__ x, const float* __restrict__ wmu,
                               const float* __restrict__ wls, const float* __restrict__ r1,
                               const float* __restrict__ bmu, const float* __restrict__ bls,
                               const float* __restrict__ r2, float* __restrict__ out) {
    __shared__ float Xs[16][64];
    __shared__ float Ws[16][64];
    int b0 = blockIdx.x * 16, o0 = blockIdx.y * 16, s = blockIdx.z;
    int tb = threadIdx.x >> 4, to = threadIdx.x & 15;
    float acc = 0.f;
    for (int k0 = 0; k0 < NIN; k0 += 64) {
        __syncthreads();
        #pragma unroll
        for (int j = 0; j < 4; ++j) {
            int e = j * 256 + threadIdx.x;
            int r = e >> 6, cc = e & 63;
            Xs[r][cc] = x[(size_t)(b0 + r) * NIN + k0 + cc];
            size_t wi = (size_t)(o0 + r) * NIN + k0 + cc;
            Ws[r][cc] = wmu[wi] + __expf(wls[wi]) * r1[(size_t)s * NIN * NOUT + wi];
        }
        __syncthreads();
        for (int k = 0; k < 64; ++k) acc += Xs[tb][k] * Ws[to][k];
    }
    int o = o0 + to;
    out[((size_t)s * NB + b0 + tb) * NOUT + o] = acc + bmu[o] + __expf(bls[o]) * r2[s * NOUT + o];
}

extern "C" void kernel_launch(void* const* d_in, const int* in_sizes, int n_in,
                              void* d_out, int out_size, void* d_ws, size_t ws_size,
                              hipStream_t stream) {
    const float* x   = (const float*)d_in[0];
    const float* wmu = (const float*)d_in[1];
    const float* wls = (const float*)d_in[2];
    const float* bmu = (const float*)d_in[3];
    const float* bls = (const float*)d_in[4];
    const float* r1  = (const float*)d_in[5];
    const float* r2  = (const float*)d_in[6];
    const int S = in_sizes[6] / NOUT;
    float* out = (float*)d_out;

    const size_t xb_b   = (size_t)NB * NIN * 2;       // 8 MB  bf16 x
    const size_t xf8_b  = (size_t)NB * NIN;           // 4 MB  fp8 x
    const size_t wmub_b = (size_t)NOUT * NIN * 2;     // 2 MB  bf16 w_mu
    const size_t y0_b   = (size_t)NB * NOUT * 4;      // 16 MB f32 y0
    const size_t bias_b = (size_t)S * NOUT * 4;
    const size_t per_s  = (size_t)NOUT * NIN;         // 1 MB fp8 per sample
    const size_t base_b = xb_b + xf8_b + wmub_b + y0_b + bias_b;

    if (ws_size < base_b + per_s) {
        dim3 gg(NB / 16, NOUT / 16, S);
        fused_fallback<<<gg, 256, 0, stream>>>(x, wmu, wls, r1, bmu, bls, r2, out);
        return;
    }

    char* ws = (char*)d_ws;
    unsigned short* xb   = (unsigned short*)ws;
    unsigned char*  xf8  = (unsigned char*)(ws + xb_b);
    unsigned short* wmub = (unsigned short*)(ws + xb_b + xf8_b);
    float*          y0   = (float*)(ws + xb_b + xf8_b + wmub_b);
    float*          bias = (float*)(ws + xb_b + xf8_b + wmub_b + y0_b);
    unsigned char*  rf8  = (unsigned char*)(ws + base_b);

    int SC = (int)((ws_size - base_b) / per_s);
    if (SC > S) SC = S;

    cvt_x_kernel<<<NB * NIN / 1024, 256, 0, stream>>>(x, xb);
    cvt_x_kernel<<<NOUT * NIN / 1024, 256, 0, stream>>>(wmu, wmub);
    cvt_x_fp8<<<NB * NIN / 1024, 256, 0, stream>>>(x, (unsigned int*)xf8);
    bias_kernel<<<(S * NOUT + 255) / 256, 256, 0, stream>>>(bmu, bls, r2, bias, S * NOUT);

    // y0 = x . w_mu^T   (bf16, 64 blocks)
    gemm256<<<64, 512, 0, stream>>>(xb, wmub, y0, 64);

    for (int s0 = 0; s0 < S; s0 += SC) {
        int sc = (S - s0 < SC) ? (S - s0) : SC;
        cvt_r1_fp8<<<sc * (NOUT * NIN / 1024), 256, 0, stream>>>(wls, r1, (unsigned int*)rf8, s0);
        int nwg = 64 * sc;
        gemm256mx<<<nwg, 512, 0, stream>>>(xf8, rf8, y0, bias, out, s0, nwg);
    }
}